// Round 3
// baseline (19020.387 us; speedup 1.0000x reference)
//
#include <hip/hip_runtime.h>
#include <hip/hip_bf16.h>
#include <math.h>

#define GN 10000
#define GE 160000
#define GT 4
#define GL 3

// ---------------------------------------------------------------------------
// Generic tiled fp32 GEMM: C[M,N] = act( gather(A)[M,K] (.* A2) @ B[K,N] + bias )
// 64x64 tile, BK=16, 256 threads, 4x4 register tile per thread.
// ---------------------------------------------------------------------------
template<bool RELU_C, bool GATHER, bool MUL>
__global__ __launch_bounds__(256) void gemm_k(
    const float* __restrict__ A, const float* __restrict__ A2,
    const int* __restrict__ idx,
    const float* __restrict__ B, const float* __restrict__ bias,
    float* __restrict__ C,
    int M, int N, int K, int lda, int ldb, int ldc)
{
  __shared__ float As[16][65];
  __shared__ float Bs[16][65];
  const int tid = threadIdx.x;
  const int brow = blockIdx.y * 64, bcol = blockIdx.x * 64;
  const int tr = ((tid >> 4) & 15) << 2;
  const int tc = (tid & 15) << 2;
  float acc[4][4] = {{0.f}};

  for (int k0 = 0; k0 < K; k0 += 16) {
    for (int i = tid; i < 64 * 16; i += 256) {
      int r = i >> 4, c = i & 15;
      int gr = brow + r, gk = k0 + c;
      float v = 0.f;
      if (gr < M && gk < K) {
        size_t ar = GATHER ? (size_t)idx[gr] : (size_t)gr;
        v = A[ar * (size_t)lda + gk];
        if (MUL) v *= A2[ar * (size_t)lda + gk];
      }
      As[c][r] = v;
    }
    for (int i = tid; i < 16 * 64; i += 256) {
      int r = i >> 6, c = i & 63;
      int gk = k0 + r, gc = bcol + c;
      Bs[r][c] = (gk < K && gc < N) ? B[(size_t)gk * ldb + gc] : 0.f;
    }
    __syncthreads();
#pragma unroll
    for (int kk = 0; kk < 16; ++kk) {
      float a[4], b[4];
#pragma unroll
      for (int i = 0; i < 4; ++i) a[i] = As[kk][tr + i];
#pragma unroll
      for (int j = 0; j < 4; ++j) b[j] = Bs[kk][tc + j];
#pragma unroll
      for (int i = 0; i < 4; ++i)
#pragma unroll
        for (int j = 0; j < 4; ++j) acc[i][j] += a[i] * b[j];
    }
    __syncthreads();
  }

#pragma unroll
  for (int i = 0; i < 4; ++i) {
    int gr = brow + tr + i;
    if (gr >= M) continue;
#pragma unroll
    for (int j = 0; j < 4; ++j) {
      int gc = bcol + tc + j;
      if (gc >= N) continue;
      float v = acc[i][j] + bias[gc];
      if (RELU_C) v = fmaxf(v, 0.f);
      C[(size_t)gr * ldc + gc] = v;
    }
  }
}

static inline void run_gemm(hipStream_t s, const float* A, const float* A2, const int* idx,
                            const float* B, const float* bias, float* C,
                            int M, int N, int K, int lda, int ldb, int ldc,
                            bool reluC, bool gather, bool mul)
{
  dim3 g((N + 63) / 64, (M + 63) / 64), b(256);
  if (gather) {
    if (reluC) gemm_k<true, true, false><<<g, b, 0, s>>>(A, A2, idx, B, bias, C, M, N, K, lda, ldb, ldc);
    else       gemm_k<false, true, false><<<g, b, 0, s>>>(A, A2, idx, B, bias, C, M, N, K, lda, ldb, ldc);
  } else if (mul) {
    gemm_k<true, false, true><<<g, b, 0, s>>>(A, A2, idx, B, bias, C, M, N, K, lda, ldb, ldc);
  } else if (reluC) {
    gemm_k<true, false, false><<<g, b, 0, s>>>(A, A2, idx, B, bias, C, M, N, K, lda, ldb, ldc);
  } else {
    gemm_k<false, false, false><<<g, b, 0, s>>>(A, A2, idx, B, bias, C, M, N, K, lda, ldb, ldc);
  }
}

// ---------------------------------------------------------------------------
// Edge sort by dst (counting sort)
// ---------------------------------------------------------------------------
__global__ void deg_kernel(const int* __restrict__ dst, int* __restrict__ deg, int E)
{
  int e = blockIdx.x * blockDim.x + threadIdx.x;
  if (e < E) atomicAdd(&deg[dst[e]], 1);
}

__global__ void scan_kernel(const int* __restrict__ deg, int* __restrict__ rowptr, int n)
{
  __shared__ int tmp[256];
  __shared__ int carry;
  if (threadIdx.x == 0) carry = 0;
  __syncthreads();
  for (int base = 0; base < n; base += 256) {
    int i = base + (int)threadIdx.x;
    int v = (i < n) ? deg[i] : 0;
    tmp[threadIdx.x] = v;
    __syncthreads();
    for (int off = 1; off < 256; off <<= 1) {
      int t = (threadIdx.x >= (unsigned)off) ? tmp[threadIdx.x - off] : 0;
      __syncthreads();
      tmp[threadIdx.x] += t;
      __syncthreads();
    }
    if (i < n) rowptr[i] = carry + tmp[threadIdx.x] - v;
    __syncthreads();
    if (threadIdx.x == 0) carry += tmp[255];
    __syncthreads();
  }
  if (threadIdx.x == 0) rowptr[n] = carry;
}

__global__ void scatter_kernel(const int* __restrict__ dst, int* __restrict__ cursor,
                               int* __restrict__ eidx, int E)
{
  int e = blockIdx.x * blockDim.x + threadIdx.x;
  if (e < E) {
    int p = atomicAdd(&cursor[dst[e]], 1);
    eidx[p] = e;
  }
}

// ---------------------------------------------------------------------------
// Aggregator init (per tower): sum=0, sumsq=0, mx=encode(-inf)=0x007FFFFF
// ---------------------------------------------------------------------------
__global__ void agg_init_kernel(float* __restrict__ s, float* __restrict__ ss,
                                unsigned* __restrict__ mx, int total)
{
  int i = blockIdx.x * blockDim.x + threadIdx.x;
  if (i >= total) return;
  s[i] = 0.f; ss[i] = 0.f; mx[i] = 0x007FFFFFu;
}

// ---------------------------------------------------------------------------
// Fused PNA conv message path for one tower, one 64-edge block (dst-sorted):
//   h  = relu([x[dst]|x[src]|enc] @ W1_t + b1_t)
//   msg = h @ W2_t + b2_t
//   segmented reduce -> atomic merge into per-node sum/sumsq/max (N x 128)
// enc is chunk-local (row = sorted position within chunk).
// ---------------------------------------------------------------------------
__global__ __launch_bounds__(256) void conv_fused_kernel(
    const float* __restrict__ x, const float* __restrict__ enc,
    const int* __restrict__ eidx, const int* __restrict__ src,
    const int* __restrict__ dst, long chunkBase, int t,
    const float* __restrict__ W1, const float* __restrict__ b1,
    const float* __restrict__ W2, const float* __restrict__ b2,
    float* __restrict__ sumb, float* __restrict__ sumsqb,
    unsigned* __restrict__ mxb)
{
  __shared__ float As[16][68];
  __shared__ float Bs[16][132];
  __shared__ float Hs[64][132];
  __shared__ int nid[64];
  __shared__ int sid[64];

  const int tid = threadIdx.x;
  const int p0 = blockIdx.x * 64;     // local position within chunk

  if (tid < 64) {
    int e = eidx[chunkBase + p0 + tid];
    nid[tid] = dst[e];
    sid[tid] = src[e];
  }
  __syncthreads();

  const int tr = ((tid >> 4) & 15) << 2;   // rows 0..60 step 4
  const int tc = (tid & 15) << 3;          // cols 0..120 step 8

  float acc[4][8];
#pragma unroll
  for (int i = 0; i < 4; ++i)
#pragma unroll
    for (int j = 0; j < 8; ++j) acc[i][j] = 0.f;

  const float* W1t = W1 + (size_t)t * 384 * 128;

  // phase 1: h = Acat @ W1_t
  for (int k0 = 0; k0 < 384; k0 += 16) {
#pragma unroll
    for (int q = 0; q < 4; ++q) {
      int i = tid + q * 256;
      int rr = i >> 4, c = i & 15;
      int gk = k0 + c;
      float v;
      if (gk < 128)       v = x[(size_t)nid[rr] * 128 + gk];
      else if (gk < 256)  v = x[(size_t)sid[rr] * 128 + (gk - 128)];
      else                v = enc[(size_t)(p0 + rr) * 128 + (gk - 256)];
      As[c][rr] = v;
    }
#pragma unroll
    for (int q = 0; q < 8; ++q) {
      int i = tid + q * 256;
      int r = i >> 7, c = i & 127;
      Bs[r][c] = W1t[(size_t)(k0 + r) * 128 + c];
    }
    __syncthreads();
#pragma unroll
    for (int kk = 0; kk < 16; ++kk) {
      float a[4], b[8];
#pragma unroll
      for (int i = 0; i < 4; ++i) a[i] = As[kk][tr + i];
#pragma unroll
      for (int j = 0; j < 8; ++j) b[j] = Bs[kk][tc + j];
#pragma unroll
      for (int i = 0; i < 4; ++i)
#pragma unroll
        for (int j = 0; j < 8; ++j) acc[i][j] += a[i] * b[j];
    }
    __syncthreads();
  }

  // h = relu(acc + b1) -> Hs
#pragma unroll
  for (int i = 0; i < 4; ++i)
#pragma unroll
    for (int j = 0; j < 8; ++j)
      Hs[tr + i][tc + j] = fmaxf(acc[i][j] + b1[t * 128 + tc + j], 0.f);

#pragma unroll
  for (int i = 0; i < 4; ++i)
#pragma unroll
    for (int j = 0; j < 8; ++j) acc[i][j] = 0.f;

  const float* W2t = W2 + (size_t)t * 128 * 128;
  __syncthreads();

  // phase 2: msg = Hs @ W2_t
  for (int k0 = 0; k0 < 128; k0 += 16) {
#pragma unroll
    for (int q = 0; q < 8; ++q) {
      int i = tid + q * 256;
      int r = i >> 7, c = i & 127;
      Bs[r][c] = W2t[(size_t)(k0 + r) * 128 + c];
    }
    __syncthreads();
#pragma unroll
    for (int kk = 0; kk < 16; ++kk) {
      float a[4], b[8];
#pragma unroll
      for (int i = 0; i < 4; ++i) a[i] = Hs[tr + i][k0 + kk];
#pragma unroll
      for (int j = 0; j < 8; ++j) b[j] = Bs[kk][tc + j];
#pragma unroll
      for (int i = 0; i < 4; ++i)
#pragma unroll
        for (int j = 0; j < 8; ++j) acc[i][j] += a[i] * b[j];
    }
    __syncthreads();
  }

  // msg -> Hs (safe: all Hs reads happened before last barrier)
#pragma unroll
  for (int i = 0; i < 4; ++i)
#pragma unroll
    for (int j = 0; j < 8; ++j)
      Hs[tr + i][tc + j] = acc[i][j] + b2[t * 128 + tc + j];
  __syncthreads();

  // segmented reduce over 64 sorted rows, one column per thread (128 cols)
  if (tid < 128) {
    int col = tid;
    int cur = nid[0];
    float s = 0.f, ssq = 0.f, m = -INFINITY;
    for (int rr = 0; rr < 64; ++rr) {
      int n = nid[rr];
      if (n != cur) {
        size_t o = (size_t)cur * 128 + col;
        atomicAdd(&sumb[o], s);
        atomicAdd(&sumsqb[o], ssq);
        unsigned ub = __float_as_uint(m);
        atomicMax(&mxb[o], (ub & 0x80000000u) ? ~ub : (ub | 0x80000000u));
        cur = n; s = 0.f; ssq = 0.f; m = -INFINITY;
      }
      float v = Hs[rr][col];
      s += v; ssq += v * v; m = fmaxf(m, v);
    }
    size_t o = (size_t)cur * 128 + col;
    atomicAdd(&sumb[o], s);
    atomicAdd(&sumsqb[o], ssq);
    unsigned ub = __float_as_uint(m);
    atomicMax(&mxb[o], (ub & 0x80000000u) ? ~ub : (ub | 0x80000000u));
  }
}

// ---------------------------------------------------------------------------
// Finalize (per tower), in place: sumb:=mean, sumsqb:=std, mxb:=max float
// ---------------------------------------------------------------------------
__global__ void finalize_kernel(
    float* __restrict__ sumb, float* __restrict__ sumsqb,
    unsigned* __restrict__ mxb, const int* __restrict__ rowptr, int total)
{
  int i = blockIdx.x * blockDim.x + threadIdx.x;
  if (i >= total) return;               // total = N*128
  int n = i >> 7;
  float cnt = fmaxf((float)(rowptr[n + 1] - rowptr[n]), 1.f);
  float mean = sumb[i] / cnt;
  float msq  = sumsqb[i] / cnt;
  float sd = sqrtf(fmaxf(msq - mean * mean, 0.f) + 1e-5f);
  unsigned u = mxb[i];
  unsigned bits = (u & 0x80000000u) ? (u & 0x7FFFFFFFu) : ~u;
  float mxv = __uint_as_float(bits);
  if ((bits & 0x7F800000u) == 0x7F800000u) mxv = 0.f;   // nonfinite -> 0
  sumb[i] = mean;
  sumsqb[i] = sd;
  mxb[i] = __float_as_uint(mxv);
}

// ---------------------------------------------------------------------------
// cat-GEMM: q1[:, t*32:] = relu([x|mean|max|std] @ W(512,32) + b)
// ---------------------------------------------------------------------------
__global__ __launch_bounds__(256) void cat_gemm_k(
    const float* __restrict__ x, const float* __restrict__ meanp,
    const float* __restrict__ mxp, const float* __restrict__ stdp,
    const float* __restrict__ B, const float* __restrict__ bias,
    float* __restrict__ C, int M)
{
  __shared__ float As[16][65];
  __shared__ float Bs[16][33];
  const int tid = threadIdx.x;
  const int brow = blockIdx.x * 64;
  const int tr = (tid >> 3) << 1;     // 0..62 step 2
  const int tc = (tid & 7) << 2;      // 0..28 step 4
  float acc[2][4] = {{0.f}};

  for (int k0 = 0; k0 < 512; k0 += 16) {
#pragma unroll
    for (int q = 0; q < 4; ++q) {
      int i = tid + q * 256;
      int r = i >> 4, c = i & 15;
      int gr = brow + r, gk = k0 + c;
      float v = 0.f;
      if (gr < M) {
        const float* sp = (gk < 128) ? x : (gk < 256) ? meanp : (gk < 384) ? mxp : stdp;
        v = sp[(size_t)gr * 128 + (gk & 127)];
      }
      As[c][r] = v;
    }
#pragma unroll
    for (int q = 0; q < 2; ++q) {
      int i = tid + q * 256;
      int r = i >> 5, c = i & 31;
      Bs[r][c] = B[(size_t)(k0 + r) * 32 + c];
    }
    __syncthreads();
#pragma unroll
    for (int kk = 0; kk < 16; ++kk) {
      float a0 = As[kk][tr], a1 = As[kk][tr + 1];
#pragma unroll
      for (int j = 0; j < 4; ++j) {
        float b = Bs[kk][tc + j];
        acc[0][j] += a0 * b;
        acc[1][j] += a1 * b;
      }
    }
    __syncthreads();
  }
#pragma unroll
  for (int i = 0; i < 2; ++i) {
    int gr = brow + tr + i;
    if (gr >= M) continue;
#pragma unroll
    for (int j = 0; j < 4; ++j)
      C[(size_t)gr * 128 + tc + j] = fmaxf(acc[i][j] + bias[tc + j], 0.f);
  }
}

// ---------------------------------------------------------------------------
// GRU elementwise combine (safe in-place: hout may alias h)
// ---------------------------------------------------------------------------
__global__ void gru_kernel(const float* __restrict__ gi, const float* __restrict__ gh,
                           const float* __restrict__ h, float* __restrict__ hout, int total)
{
  int i = blockIdx.x * blockDim.x + threadIdx.x;
  if (i >= total) return;
  int n = i >> 7, c = i & 127;
  const float* gin = gi + (size_t)n * 384;
  const float* ghn = gh + (size_t)n * 384;
  float ir = gin[c], iz = gin[128 + c], inn = gin[256 + c];
  float hr = ghn[c], hz = ghn[128 + c], hn = ghn[256 + c];
  float r = 1.f / (1.f + __expf(-(ir + hr)));
  float z = 1.f / (1.f + __expf(-(iz + hz)));
  float nn = tanhf(inn + r * hn);
  hout[i] = (1.f - z) * nn + z * h[i];
}

// ---------------------------------------------------------------------------
// Concat [med(M,64) | ea(M,64)] -> out(M,128)
// ---------------------------------------------------------------------------
__global__ void concat_kernel(const float* __restrict__ a, const float* __restrict__ b,
                              float* __restrict__ out, long total)
{
  long i = (long)blockIdx.x * blockDim.x + threadIdx.x;
  if (i >= total) return;
  long e = i >> 7;
  int c = (int)(i & 127);
  out[i] = (c < 64) ? a[e * 64 + c] : b[e * 64 + (c - 64)];
}

// ---------------------------------------------------------------------------
extern "C" void kernel_launch(void* const* d_in, const int* in_sizes, int n_in,
                              void* d_out, int out_size, void* d_ws, size_t ws_size,
                              hipStream_t stream)
{
  const int N_ = GN, E_ = GE;

  const float* x_in   = (const float*)d_in[0];
  const int*   src    = (const int*)d_in[1];
  const int*   dst    = src + E_;
  const float* ea_in  = (const float*)d_in[2];
  const float* enc_W  = (const float*)d_in[3];
  const float* enc_b  = (const float*)d_in[4];
  const float* pre_W1 = (const float*)d_in[5];
  const float* pre_b1 = (const float*)d_in[6];
  const float* pre_W2 = (const float*)d_in[7];
  const float* pre_b2 = (const float*)d_in[8];
  const float* post_W1 = (const float*)d_in[9];
  const float* post_b1 = (const float*)d_in[10];
  const float* post_W2 = (const float*)d_in[11];
  const float* post_b2 = (const float*)d_in[12];
  const float* lin_W  = (const float*)d_in[13];
  const float* lin_b  = (const float*)d_in[14];
  const float* gru_Wi = (const float*)d_in[15];
  const float* gru_Wh = (const float*)d_in[16];
  const float* gru_bi = (const float*)d_in[17];
  const float* gru_bh = (const float*)d_in[18];
  const float* fcu_W1 = (const float*)d_in[19];
  const float* fcu_b1 = (const float*)d_in[20];
  const float* fcu_W2 = (const float*)d_in[21];
  const float* fcu_b2 = (const float*)d_in[22];
  const float* fcv_W1 = (const float*)d_in[23];
  const float* fcv_b1 = (const float*)d_in[24];
  const float* fcv_W2 = (const float*)d_in[25];
  const float* fcv_b2 = (const float*)d_in[26];
  const float* fc_W1  = (const float*)d_in[27];
  const float* fc_b1  = (const float*)d_in[28];
  const float* fc_W2  = (const float*)d_in[29];
  const float* fc_b2  = (const float*)d_in[30];
  const float* eu_W1  = (const float*)d_in[31];
  const float* eu_b1  = (const float*)d_in[32];
  const float* eu_W2  = (const float*)d_in[33];
  const float* eu_b2  = (const float*)d_in[34];

  // ---- workspace arena ----
  size_t used = 0;
  char* w = (char*)d_ws;
  auto alloc = [&](size_t bytes) {
    char* p = w + used;
    used += (bytes + 255) & ~(size_t)255;
    return p;
  };
  float*    sumb   = (float*)alloc((size_t)N_ * 128 * 4);
  float*    sumsqb = (float*)alloc((size_t)N_ * 128 * 4);
  unsigned* mxb    = (unsigned*)alloc((size_t)N_ * 128 * 4);
  float*    q1   = (float*)alloc((size_t)N_ * 128 * 4);
  float*    q2   = (float*)alloc((size_t)N_ * 128 * 4);
  float*    mb   = (float*)alloc((size_t)N_ * 128 * 4);
  float*    gib  = (float*)alloc((size_t)N_ * 384 * 4);
  float*    ghb  = (float*)alloc((size_t)N_ * 384 * 4);
  float*    Hb   = (float*)alloc((size_t)N_ * 128 * 4);
  int*      eidx   = (int*)alloc((size_t)E_ * 4);
  int*      degb   = (int*)alloc((size_t)(N_ + 1) * 4);
  int*      rowptr = (int*)alloc((size_t)(N_ + 1) * 4);
  int*      cursor = (int*)alloc((size_t)(N_ + 1) * 4);

  // chunk size from remaining ws: 3 bufs of Ec x 256 floats
  size_t avail = (ws_size > used + 4096) ? (ws_size - used - 4096) : 0;
  long Ec = (long)(avail / (3 * 256 * 4));
  if (Ec > E_) Ec = E_;
  Ec &= ~255L;
  if (Ec < 256) return;   // ws too small: fail cleanly (zero-output signature)
  float* C1 = (float*)alloc((size_t)Ec * 256 * 4);
  float* C2 = (float*)alloc((size_t)Ec * 256 * 4);
  float* C3 = (float*)alloc((size_t)Ec * 256 * 4);
  if (used > ws_size) return;
  const int nchunks = (int)((E_ + Ec - 1) / Ec);

  // EA state lives directly in the output buffer (fp32): out[N*128 : N*128+E*64]
  float* out = (float*)d_out;
  float* EAp = out + (size_t)N_ * 128;

  // ---- sort edges by dst (counting sort) ----
  hipMemsetAsync(degb, 0, (size_t)N_ * 4, stream);
  deg_kernel<<<(E_ + 255) / 256, 256, 0, stream>>>(dst, degb, E_);
  scan_kernel<<<1, 256, 0, stream>>>(degb, rowptr, N_);
  hipMemcpyAsync(cursor, rowptr, (size_t)N_ * 4, hipMemcpyDeviceToDevice, stream);
  scatter_kernel<<<(E_ + 255) / 256, 256, 0, stream>>>(dst, cursor, eidx, E_);

  const float* x_cur = x_in;
  const float* ea_cur = ea_in;

  for (int l = 0; l < GL; ++l) {
    // ---- PNA conv, per tower ----
    for (int t = 0; t < GT; ++t) {
      agg_init_kernel<<<(N_ * 128 + 255) / 256, 256, 0, stream>>>(sumb, sumsqb, mxb, N_ * 128);
      for (int c = 0; c < nchunks; ++c) {
        long p0 = (long)c * Ec;
        int Mc = (int)(((long)E_ - p0 < Ec) ? ((long)E_ - p0) : Ec);
        // enc chunk: gather ea rows (sorted order) @ enc_W[l] + b -> C1 (Mc,128)
        run_gemm(stream, ea_cur, nullptr, eidx + p0, enc_W + (size_t)l * 64 * 128,
                 enc_b + (size_t)l * 128, C1, Mc, 128, 64, 64, 128, 128, false, true, false);
        conv_fused_kernel<<<Mc / 64, 256, 0, stream>>>(
            x_cur, C1, eidx, src, dst, p0, t,
            pre_W1 + (size_t)l * GT * 384 * 128, pre_b1 + (size_t)l * GT * 128,
            pre_W2 + (size_t)l * GT * 128 * 128, pre_b2 + (size_t)l * GT * 128,
            sumb, sumsqb, mxb);
      }
      finalize_kernel<<<(N_ * 128 + 255) / 256, 256, 0, stream>>>(
          sumb, sumsqb, mxb, rowptr, N_ * 128);
      // post-MLP W1 (per tower): q1[:, t*32:] = relu(cat @ W1 + b1)
      cat_gemm_k<<<(N_ + 63) / 64, 256, 0, stream>>>(
          x_cur, sumb, (const float*)mxb, sumsqb,
          post_W1 + ((size_t)l * GT + t) * 512 * 32,
          post_b1 + ((size_t)l * GT + t) * 32,
          q1 + t * 32, N_);
      // post-MLP W2: q2[:, t*32:] = q1_t @ W2 + b2
      run_gemm(stream, q1 + t * 32, nullptr, nullptr,
               post_W2 + ((size_t)l * GT + t) * 32 * 32,
               post_b2 + ((size_t)l * GT + t) * 32,
               q2 + t * 32, N_, 32, 32, 128, 32, 128, false, false, false);
    }
    // lin: m = q2 @ lin_W[l] + lin_b[l]
    run_gemm(stream, q2, nullptr, nullptr, lin_W + (size_t)l * 128 * 128,
             lin_b + (size_t)l * 128, mb, N_, 128, 128, 128, 128, 128, false, false, false);

    // ---- GRU ----
    run_gemm(stream, mb, nullptr, nullptr, gru_Wi, gru_bi, gib,
             N_, 384, 128, 128, 384, 384, false, false, false);
    run_gemm(stream, x_cur, nullptr, nullptr, gru_Wh, gru_bh, ghb,
             N_, 384, 128, 128, 384, 384, false, false, false);
    gru_kernel<<<(N_ * 128 + 255) / 256, 256, 0, stream>>>(gib, ghb, x_cur, Hb, N_ * 128);

    // ---- edge update (chunked; EA updated in place chunk-by-chunk) ----
    for (int c = 0; c < nchunks; ++c) {
      long e0 = (long)c * Ec;
      int Mc = (int)(((long)E_ - e0 < Ec) ? ((long)E_ - e0) : Ec);
      run_gemm(stream, Hb, nullptr, src + e0, fcu_W1, fcu_b1, C1,
               Mc, 256, 128, 128, 256, 256, true, true, false);
      run_gemm(stream, C1, nullptr, nullptr, fcu_W2, fcu_b2, C2,
               Mc, 256, 256, 256, 256, 256, true, false, false);
      run_gemm(stream, Hb, nullptr, dst + e0, fcv_W1, fcv_b1, C1,
               Mc, 256, 128, 128, 256, 256, true, true, false);
      run_gemm(stream, C1, nullptr, nullptr, fcv_W2, fcv_b2, C3,
               Mc, 256, 256, 256, 256, 256, true, false, false);
      run_gemm(stream, C2, C3, nullptr, fc_W1, fc_b1, C1,
               Mc, 256, 256, 256, 256, 256, true, false, true);
      run_gemm(stream, C1, nullptr, nullptr, fc_W2, fc_b2, C2,
               Mc, 64, 256, 256, 64, 64, true, false, false);
      concat_kernel<<<(int)(((long)Mc * 128 + 255) / 256), 256, 0, stream>>>(
          C2, ea_cur + e0 * 64, C3, (long)Mc * 128);
      run_gemm(stream, C3, nullptr, nullptr, eu_W1, eu_b1, C1,
               Mc, 128, 128, 128, 128, 128, true, false, false);
      run_gemm(stream, C1, nullptr, nullptr, eu_W2, eu_b2, EAp + e0 * 64,
               Mc, 64, 128, 128, 64, 64, false, false, false);
    }

    x_cur = Hb;       // GRU is in-place for l >= 1
    ea_cur = EAp;     // EA in-place for l >= 1
  }

  // outputs: [out (N*128) | ea (already in place) | out (N*128)]
  hipMemcpyAsync(out, x_cur, (size_t)N_ * 128 * 4, hipMemcpyDeviceToDevice, stream);
  hipMemcpyAsync(out + (size_t)N_ * 128 + (size_t)E_ * 64, x_cur,
                 (size_t)N_ * 128 * 4, hipMemcpyDeviceToDevice, stream);
}

// Round 4
// 4417.565 us; speedup vs baseline: 4.3056x; 4.3056x over previous
//
#include <hip/hip_runtime.h>
#include <hip/hip_bf16.h>
#include <math.h>

#define GN 10000
#define GE 160000
#define GT 4
#define GL 3

typedef __attribute__((ext_vector_type(8))) short short8;
typedef __attribute__((ext_vector_type(4))) float f32x4;
typedef unsigned short u16;

__device__ __forceinline__ u16 f2b(float f) {
  unsigned u = __float_as_uint(f);
  unsigned r = (u + 0x7FFFu + ((u >> 16) & 1u)) >> 16;
  return (u16)r;
}
__device__ __forceinline__ float b2f(u16 b) {
  return __uint_as_float(((unsigned)b) << 16);
}

// ---------------------------------------------------------------------------
// fp32 tiled GEMM (node-side small GEMMs + enc): 64x64 tile, BK=16.
// C = act( gather(A) @ B + bias ); OUTB: write bf16 instead of fp32.
// ---------------------------------------------------------------------------
template<bool RELU_C, bool GATHER, bool OUTB>
__global__ __launch_bounds__(256) void gemm_k(
    const float* __restrict__ A, const int* __restrict__ idx,
    const float* __restrict__ B, const float* __restrict__ bias,
    void* __restrict__ Cv,
    int M, int N, int K, int lda, int ldb, int ldc)
{
  __shared__ float As[16][65];
  __shared__ float Bs[16][65];
  const int tid = threadIdx.x;
  const int brow = blockIdx.y * 64, bcol = blockIdx.x * 64;
  const int tr = ((tid >> 4) & 15) << 2;
  const int tc = (tid & 15) << 2;
  float acc[4][4] = {{0.f}};

  for (int k0 = 0; k0 < K; k0 += 16) {
    for (int i = tid; i < 64 * 16; i += 256) {
      int r = i >> 4, c = i & 15;
      int gr = brow + r, gk = k0 + c;
      float v = 0.f;
      if (gr < M && gk < K) {
        size_t ar = GATHER ? (size_t)idx[gr] : (size_t)gr;
        v = A[ar * (size_t)lda + gk];
      }
      As[c][r] = v;
    }
    for (int i = tid; i < 16 * 64; i += 256) {
      int r = i >> 6, c = i & 63;
      int gk = k0 + r, gc = bcol + c;
      Bs[r][c] = (gk < K && gc < N) ? B[(size_t)gk * ldb + gc] : 0.f;
    }
    __syncthreads();
#pragma unroll
    for (int kk = 0; kk < 16; ++kk) {
      float a[4], b[4];
#pragma unroll
      for (int i = 0; i < 4; ++i) a[i] = As[kk][tr + i];
#pragma unroll
      for (int j = 0; j < 4; ++j) b[j] = Bs[kk][tc + j];
#pragma unroll
      for (int i = 0; i < 4; ++i)
#pragma unroll
        for (int j = 0; j < 4; ++j) acc[i][j] += a[i] * b[j];
    }
    __syncthreads();
  }

#pragma unroll
  for (int i = 0; i < 4; ++i) {
    int gr = brow + tr + i;
    if (gr >= M) continue;
#pragma unroll
    for (int j = 0; j < 4; ++j) {
      int gc = bcol + tc + j;
      if (gc >= N) continue;
      float v = acc[i][j] + bias[gc];
      if (RELU_C) v = fmaxf(v, 0.f);
      if (OUTB) ((u16*)Cv)[(size_t)gr * ldc + gc] = f2b(v);
      else      ((float*)Cv)[(size_t)gr * ldc + gc] = v;
    }
  }
}

// ---------------------------------------------------------------------------
// bf16 MFMA GEMM: C[M,N] = act( gather(A)[M,K] (.*A2) @ Bt^T + bias )
// A row-major bf16 (lda), Bt is [N][K] bf16 (pre-transposed weights).
// 64x64 tile, BK=64, 256 thr = 4 waves (2x2), mfma_f32_16x16x32_bf16.
// LDS XOR-swizzle (byte ^= (row&7)<<4) to avoid 16-way bank conflicts.
// Requires: M%64==0, N%64==0, K%64==0.
// ---------------------------------------------------------------------------
template<bool RELU, bool GATHER, bool MUL, bool OUTB>
__global__ __launch_bounds__(256) void mgemm_k(
    const u16* __restrict__ A, const u16* __restrict__ A2,
    const int* __restrict__ idx,
    const u16* __restrict__ Bt, const float* __restrict__ bias,
    void* __restrict__ Cv,
    int M, int N, int K, int lda, int ldc)
{
  __shared__ u16 As[64 * 64];
  __shared__ u16 Bs[64 * 64];
  __shared__ int ridx[64];
  const int tid = threadIdx.x;
  const int brow = blockIdx.y * 64, bcol = blockIdx.x * 64;
  const int wid = tid >> 6, lane = tid & 63;
  const int wr = wid >> 1, wc = wid & 1;
  const int lrow = lane & 15, lk8 = (lane >> 4) * 8;

  if (tid < 64) ridx[tid] = GATHER ? idx[brow + tid] : (brow + tid);
  __syncthreads();

  f32x4 acc[2][2] = {};

  for (int k0 = 0; k0 < K; k0 += 64) {
    // stage A (64 x 64 bf16), 2 x 16B per thread
#pragma unroll
    for (int s = 0; s < 2; ++s) {
      int c = tid + s * 256;
      int r = c >> 3, kq = (c & 7) * 8;
      const u16* sp = A + (size_t)ridx[r] * lda + k0 + kq;
      short8 v = *(const short8*)sp;
      if (MUL) {
        const u16* sp2 = A2 + (size_t)ridx[r] * lda + k0 + kq;
        short8 v2 = *(const short8*)sp2;
#pragma unroll
        for (int e = 0; e < 8; ++e)
          v[e] = (short)f2b(b2f((u16)v[e]) * b2f((u16)v2[e]));
      }
      int byt = (r * 128 + kq * 2) ^ ((r & 7) << 4);
      *(short8*)((char*)As + byt) = v;
    }
    // stage Bt (64 out-cols x 64 k)
#pragma unroll
    for (int s = 0; s < 2; ++s) {
      int c = tid + s * 256;
      int r = c >> 3, kq = (c & 7) * 8;
      const u16* sp = Bt + (size_t)(bcol + r) * K + k0 + kq;
      short8 v = *(const short8*)sp;
      int byt = (r * 128 + kq * 2) ^ ((r & 7) << 4);
      *(short8*)((char*)Bs + byt) = v;
    }
    __syncthreads();
#pragma unroll
    for (int ks = 0; ks < 2; ++ks) {
      short8 a[2], b[2];
#pragma unroll
      for (int m = 0; m < 2; ++m) {
        int r = wr * 32 + m * 16 + lrow;
        int kk = ks * 32 + lk8;
        int byt = (r * 128 + kk * 2) ^ ((r & 7) << 4);
        a[m] = *(const short8*)((const char*)As + byt);
      }
#pragma unroll
      for (int n = 0; n < 2; ++n) {
        int r = wc * 32 + n * 16 + lrow;
        int kk = ks * 32 + lk8;
        int byt = (r * 128 + kk * 2) ^ ((r & 7) << 4);
        b[n] = *(const short8*)((const char*)Bs + byt);
      }
#pragma unroll
      for (int m = 0; m < 2; ++m)
#pragma unroll
        for (int n = 0; n < 2; ++n)
          acc[m][n] = __builtin_amdgcn_mfma_f32_16x16x32_bf16(a[m], b[n], acc[m][n], 0, 0, 0);
    }
    __syncthreads();
  }

  // epilogue: C/D layout col=lane&15, row=(lane>>4)*4+reg
#pragma unroll
  for (int m = 0; m < 2; ++m)
#pragma unroll
    for (int n = 0; n < 2; ++n) {
      int col = bcol + wc * 32 + n * 16 + (lane & 15);
      float bv = bias[col];
#pragma unroll
      for (int j = 0; j < 4; ++j) {
        int row = brow + wr * 32 + m * 16 + (lane >> 4) * 4 + j;
        float v = acc[m][n][j] + bv;
        if (RELU) v = fmaxf(v, 0.f);
        if (OUTB) ((u16*)Cv)[(size_t)row * ldc + col] = f2b(v);
        else      ((float*)Cv)[(size_t)row * ldc + col] = v;
      }
    }
}

// ---------------------------------------------------------------------------
// Edge sort by dst (counting sort)
// ---------------------------------------------------------------------------
__global__ void deg_kernel(const int* __restrict__ dst, int* __restrict__ deg, int E)
{
  int e = blockIdx.x * blockDim.x + threadIdx.x;
  if (e < E) atomicAdd(&deg[dst[e]], 1);
}

__global__ void scan_kernel(const int* __restrict__ deg, int* __restrict__ rowptr, int n)
{
  __shared__ int tmp[256];
  __shared__ int carry;
  if (threadIdx.x == 0) carry = 0;
  __syncthreads();
  for (int base = 0; base < n; base += 256) {
    int i = base + (int)threadIdx.x;
    int v = (i < n) ? deg[i] : 0;
    tmp[threadIdx.x] = v;
    __syncthreads();
    for (int off = 1; off < 256; off <<= 1) {
      int t = (threadIdx.x >= (unsigned)off) ? tmp[threadIdx.x - off] : 0;
      __syncthreads();
      tmp[threadIdx.x] += t;
      __syncthreads();
    }
    if (i < n) rowptr[i] = carry + tmp[threadIdx.x] - v;
    __syncthreads();
    if (threadIdx.x == 0) carry += tmp[255];
    __syncthreads();
  }
  if (threadIdx.x == 0) rowptr[n] = carry;
}

__global__ void scatter_kernel(const int* __restrict__ dst, int* __restrict__ cursor,
                               int* __restrict__ eidx, int E)
{
  int e = blockIdx.x * blockDim.x + threadIdx.x;
  if (e < E) {
    int p = atomicAdd(&cursor[dst[e]], 1);
    eidx[p] = e;
  }
}

// ---------------------------------------------------------------------------
// weight transpose+convert: W (K x N fp32) -> Wt (N x K bf16)
// ---------------------------------------------------------------------------
__global__ void wtb_kernel(const float* __restrict__ W, u16* __restrict__ Wt, int K, int N)
{
  int i = blockIdx.x * blockDim.x + threadIdx.x;
  if (i >= K * N) return;
  int k = i / N, n = i % N;
  Wt[(size_t)n * K + k] = f2b(W[i]);
}

// fp32 -> bf16 convert
__global__ void f2b_kernel(const float* __restrict__ in, u16* __restrict__ out, int n)
{
  int i = blockIdx.x * blockDim.x + threadIdx.x;
  if (i < n) out[i] = f2b(in[i]);
}

// ---------------------------------------------------------------------------
// Build Acat (bf16) cols 0..255 for a chunk (sorted order): [xb[dst] | xb[src]]
// each thread copies 8 bf16 (16B). cols 256..383 (enc) written by gemm_k.
// ---------------------------------------------------------------------------
__global__ void build_acat_kernel(const u16* __restrict__ xb,
                                  const int* __restrict__ eidx,
                                  const int* __restrict__ srcA,
                                  const int* __restrict__ dstA,
                                  long base, int Mc, u16* __restrict__ Acat)
{
  int i = blockIdx.x * blockDim.x + threadIdx.x;
  int total = Mc * 32;
  if (i >= total) return;
  int p = i >> 5, q = i & 31;
  int e = eidx[base + p];
  int c0 = q * 8;
  const u16* sp = (c0 < 128) ? (xb + (size_t)dstA[e] * 128 + c0)
                             : (xb + (size_t)srcA[e] * 128 + (c0 - 128));
  *(int4*)(Acat + (size_t)p * 384 + c0) = *(const int4*)sp;
}

// ---------------------------------------------------------------------------
// Aggregator init: sum=0, sumsq=0, mx=encode(-inf)
// ---------------------------------------------------------------------------
__global__ void agg_init_kernel(float* __restrict__ s, float* __restrict__ ss,
                                unsigned* __restrict__ mx, int total)
{
  int i = blockIdx.x * blockDim.x + threadIdx.x;
  if (i >= total) return;
  s[i] = 0.f; ss[i] = 0.f; mx[i] = 0x007FFFFFu;
}

// ---------------------------------------------------------------------------
// Sorted-segment merge of a chunk's msg (fp32, Mc x 128) into per-node
// sum / sumsq / max accumulators. 64 rows per block, 128 threads (col each).
// ---------------------------------------------------------------------------
__global__ __launch_bounds__(128) void agg_merge_kernel(
    const float* __restrict__ msg, const int* __restrict__ eidx,
    const int* __restrict__ dst, long base,
    float* __restrict__ sumb, float* __restrict__ sumsqb,
    unsigned* __restrict__ mxb)
{
  __shared__ int nid[64];
  const int tid = threadIdx.x;
  const long p0 = (long)blockIdx.x * 64;
  if (tid < 64) nid[tid] = dst[eidx[base + p0 + tid]];
  __syncthreads();
  int col = tid;
  int cur = nid[0];
  float s = 0.f, ssq = 0.f, m = -INFINITY;
  for (int rr = 0; rr < 64; ++rr) {
    int n = nid[rr];
    if (n != cur) {
      size_t o = (size_t)cur * 128 + col;
      atomicAdd(&sumb[o], s);
      atomicAdd(&sumsqb[o], ssq);
      unsigned ub = __float_as_uint(m);
      atomicMax(&mxb[o], (ub & 0x80000000u) ? ~ub : (ub | 0x80000000u));
      cur = n; s = 0.f; ssq = 0.f; m = -INFINITY;
    }
    float v = msg[(size_t)(p0 + rr) * 128 + col];
    s += v; ssq += v * v; m = fmaxf(m, v);
  }
  size_t o = (size_t)cur * 128 + col;
  atomicAdd(&sumb[o], s);
  atomicAdd(&sumsqb[o], ssq);
  unsigned ub = __float_as_uint(m);
  atomicMax(&mxb[o], (ub & 0x80000000u) ? ~ub : (ub | 0x80000000u));
}

// ---------------------------------------------------------------------------
// Finalize (per tower), in place: sumb:=mean, sumsqb:=std, mxb:=max float
// ---------------------------------------------------------------------------
__global__ void finalize_kernel(
    float* __restrict__ sumb, float* __restrict__ sumsqb,
    unsigned* __restrict__ mxb, const int* __restrict__ rowptr, int total)
{
  int i = blockIdx.x * blockDim.x + threadIdx.x;
  if (i >= total) return;               // total = N*128
  int n = i >> 7;
  float cnt = fmaxf((float)(rowptr[n + 1] - rowptr[n]), 1.f);
  float mean = sumb[i] / cnt;
  float msq  = sumsqb[i] / cnt;
  float sd = sqrtf(fmaxf(msq - mean * mean, 0.f) + 1e-5f);
  unsigned u = mxb[i];
  unsigned bits = (u & 0x80000000u) ? (u & 0x7FFFFFFFu) : ~u;
  float mxv = __uint_as_float(bits);
  if ((bits & 0x7F800000u) == 0x7F800000u) mxv = 0.f;
  sumb[i] = mean;
  sumsqb[i] = sd;
  mxb[i] = __float_as_uint(mxv);
}

// ---------------------------------------------------------------------------
// cat-GEMM: q1[:, t*32:] = relu([x|mean|max|std] @ W(512,32) + b)
// ---------------------------------------------------------------------------
__global__ __launch_bounds__(256) void cat_gemm_k(
    const float* __restrict__ x, const float* __restrict__ meanp,
    const float* __restrict__ mxp, const float* __restrict__ stdp,
    const float* __restrict__ B, const float* __restrict__ bias,
    float* __restrict__ C, int M)
{
  __shared__ float As[16][65];
  __shared__ float Bs[16][33];
  const int tid = threadIdx.x;
  const int brow = blockIdx.x * 64;
  const int tr = (tid >> 3) << 1;
  const int tc = (tid & 7) << 2;
  float acc[2][4] = {{0.f}};

  for (int k0 = 0; k0 < 512; k0 += 16) {
#pragma unroll
    for (int q = 0; q < 4; ++q) {
      int i = tid + q * 256;
      int r = i >> 4, c = i & 15;
      int gr = brow + r, gk = k0 + c;
      float v = 0.f;
      if (gr < M) {
        const float* sp = (gk < 128) ? x : (gk < 256) ? meanp : (gk < 384) ? mxp : stdp;
        v = sp[(size_t)gr * 128 + (gk & 127)];
      }
      As[c][r] = v;
    }
#pragma unroll
    for (int q = 0; q < 2; ++q) {
      int i = tid + q * 256;
      int r = i >> 5, c = i & 31;
      Bs[r][c] = B[(size_t)(k0 + r) * 32 + c];
    }
    __syncthreads();
#pragma unroll
    for (int kk = 0; kk < 16; ++kk) {
      float a0 = As[kk][tr], a1 = As[kk][tr + 1];
#pragma unroll
      for (int j = 0; j < 4; ++j) {
        float b = Bs[kk][tc + j];
        acc[0][j] += a0 * b;
        acc[1][j] += a1 * b;
      }
    }
    __syncthreads();
  }
#pragma unroll
  for (int i = 0; i < 2; ++i) {
    int gr = brow + tr + i;
    if (gr >= M) continue;
#pragma unroll
    for (int j = 0; j < 4; ++j)
      C[(size_t)gr * 128 + tc + j] = fmaxf(acc[i][j] + bias[tc + j], 0.f);
  }
}

// ---------------------------------------------------------------------------
// GRU elementwise combine (in-place safe)
// ---------------------------------------------------------------------------
__global__ void gru_kernel(const float* __restrict__ gi, const float* __restrict__ gh,
                           const float* __restrict__ h, float* __restrict__ hout, int total)
{
  int i = blockIdx.x * blockDim.x + threadIdx.x;
  if (i >= total) return;
  int n = i >> 7, c = i & 127;
  const float* gin = gi + (size_t)n * 384;
  const float* ghn = gh + (size_t)n * 384;
  float ir = gin[c], iz = gin[128 + c], inn = gin[256 + c];
  float hr = ghn[c], hz = ghn[128 + c], hn = ghn[256 + c];
  float r = 1.f / (1.f + __expf(-(ir + hr)));
  float z = 1.f / (1.f + __expf(-(iz + hz)));
  float nn = tanhf(inn + r * hn);
  hout[i] = (1.f - z) * nn + z * h[i];
}

// ---------------------------------------------------------------------------
// ecat = [med bf16 (M,64) | bf16(ea fp32) (M,64)] -> out bf16 (M,128)
// ---------------------------------------------------------------------------
__global__ void concat_b_kernel(const u16* __restrict__ med, const float* __restrict__ ea,
                                u16* __restrict__ out, long total)
{
  long i = (long)blockIdx.x * blockDim.x + threadIdx.x;
  if (i >= total) return;
  long e = i >> 7;
  int c = (int)(i & 127);
  out[i] = (c < 64) ? med[e * 64 + c] : f2b(ea[e * 64 + (c - 64)]);
}

// ---------------------------------------------------------------------------
extern "C" void kernel_launch(void* const* d_in, const int* in_sizes, int n_in,
                              void* d_out, int out_size, void* d_ws, size_t ws_size,
                              hipStream_t stream)
{
  const int N_ = GN, E_ = GE;

  const float* x_in   = (const float*)d_in[0];
  const int*   src    = (const int*)d_in[1];
  const int*   dst    = src + E_;
  const float* ea_in  = (const float*)d_in[2];
  const float* enc_W  = (const float*)d_in[3];
  const float* enc_b  = (const float*)d_in[4];
  const float* pre_W1 = (const float*)d_in[5];
  const float* pre_b1 = (const float*)d_in[6];
  const float* pre_W2 = (const float*)d_in[7];
  const float* pre_b2 = (const float*)d_in[8];
  const float* post_W1 = (const float*)d_in[9];
  const float* post_b1 = (const float*)d_in[10];
  const float* post_W2 = (const float*)d_in[11];
  const float* post_b2 = (const float*)d_in[12];
  const float* lin_W  = (const float*)d_in[13];
  const float* lin_b  = (const float*)d_in[14];
  const float* gru_Wi = (const float*)d_in[15];
  const float* gru_Wh = (const float*)d_in[16];
  const float* gru_bi = (const float*)d_in[17];
  const float* gru_bh = (const float*)d_in[18];
  const float* fcu_W1 = (const float*)d_in[19];
  const float* fcu_b1 = (const float*)d_in[20];
  const float* fcu_W2 = (const float*)d_in[21];
  const float* fcu_b2 = (const float*)d_in[22];
  const float* fcv_W1 = (const float*)d_in[23];
  const float* fcv_b1 = (const float*)d_in[24];
  const float* fcv_W2 = (const float*)d_in[25];
  const float* fcv_b2 = (const float*)d_in[26];
  const float* fc_W1  = (const float*)d_in[27];
  const float* fc_b1  = (const float*)d_in[28];
  const float* fc_W2  = (const float*)d_in[29];
  const float* fc_b2  = (const float*)d_in[30];
  const float* eu_W1  = (const float*)d_in[31];
  const float* eu_b1  = (const float*)d_in[32];
  const float* eu_W2  = (const float*)d_in[33];
  const float* eu_b2  = (const float*)d_in[34];

  // ---- workspace arena ----
  size_t used = 0;
  char* w = (char*)d_ws;
  auto alloc = [&](size_t bytes) {
    char* p = w + used;
    used += (bytes + 255) & ~(size_t)255;
    return p;
  };
  // aggregation accumulators: 4 towers, [t][n][128]
  float*    sumb   = (float*)alloc((size_t)N_ * 512 * 4);
  float*    sumsqb = (float*)alloc((size_t)N_ * 512 * 4);
  unsigned* mxb    = (unsigned*)alloc((size_t)N_ * 512 * 4);
  float*    q1   = (float*)alloc((size_t)N_ * 128 * 4);
  float*    q2   = (float*)alloc((size_t)N_ * 128 * 4);
  float*    mb   = (float*)alloc((size_t)N_ * 128 * 4);
  float*    gib  = (float*)alloc((size_t)N_ * 384 * 4);
  float*    ghb  = (float*)alloc((size_t)N_ * 384 * 4);
  float*    Hb   = (float*)alloc((size_t)N_ * 128 * 4);
  u16*      xb   = (u16*)alloc((size_t)N_ * 128 * 2);
  // bf16 transposed weights
  u16* preW1t = (u16*)alloc((size_t)GL * GT * 128 * 384 * 2);
  u16* preW2t = (u16*)alloc((size_t)GL * GT * 128 * 128 * 2);
  u16* fcuW1t = (u16*)alloc((size_t)256 * 128 * 2);
  u16* fcuW2t = (u16*)alloc((size_t)256 * 256 * 2);
  u16* fcvW1t = (u16*)alloc((size_t)256 * 128 * 2);
  u16* fcvW2t = (u16*)alloc((size_t)256 * 256 * 2);
  u16* fcW1t  = (u16*)alloc((size_t)256 * 256 * 2);
  u16* fcW2t  = (u16*)alloc((size_t)64 * 256 * 2);
  u16* euW1t  = (u16*)alloc((size_t)128 * 128 * 2);
  u16* euW2t  = (u16*)alloc((size_t)64 * 128 * 2);
  int* eidx   = (int*)alloc((size_t)E_ * 4);
  int* degb   = (int*)alloc((size_t)(N_ + 1) * 4);
  int* rowptr = (int*)alloc((size_t)(N_ + 1) * 4);
  int* cursor = (int*)alloc((size_t)(N_ + 1) * 4);

  // chunk arena: 1536 B per row (union of conv and edge-chain phases)
  size_t avail = (ws_size > used + 4096) ? (ws_size - used - 4096) : 0;
  long Ec = (long)(avail / 1536);
  if (Ec > E_) Ec = E_;
  Ec &= ~255L;
  if (Ec < 256) return;   // ws too small: fail cleanly
  char* arena = alloc((size_t)Ec * 1536);
  if (used > ws_size) return;
  const int nchunks = (int)((E_ + Ec - 1) / Ec);
  // conv-phase layout
  u16*   Acatb = (u16*)arena;                        // Ec x 384 bf16 (768B/row)
  u16*   hb    = (u16*)(arena + (size_t)Ec * 768);   // Ec x 128 bf16 (256B/row)
  float* msgf  = (float*)(arena + (size_t)Ec * 1024);// Ec x 128 f32  (512B/row)
  // edge-phase layout
  u16* C1b = (u16*)arena;                            // Ec x 256 bf16
  u16* C2b = (u16*)(arena + (size_t)Ec * 512);
  u16* C3b = (u16*)(arena + (size_t)Ec * 1024);

  float* out = (float*)d_out;
  float* EAp = out + (size_t)N_ * 128;               // ea state lives in d_out

  // ---- one-time: sort edges by dst; transpose-convert weights; xb ----
  hipMemsetAsync(degb, 0, (size_t)N_ * 4, stream);
  deg_kernel<<<(E_ + 255) / 256, 256, 0, stream>>>(dst, degb, E_);
  scan_kernel<<<1, 256, 0, stream>>>(degb, rowptr, N_);
  hipMemcpyAsync(cursor, rowptr, (size_t)N_ * 4, hipMemcpyDeviceToDevice, stream);
  scatter_kernel<<<(E_ + 255) / 256, 256, 0, stream>>>(dst, cursor, eidx, E_);

  for (int l = 0; l < GL; ++l)
    for (int t = 0; t < GT; ++t) {
      wtb_kernel<<<(384 * 128 + 255) / 256, 256, 0, stream>>>(
          pre_W1 + ((size_t)l * GT + t) * 384 * 128,
          preW1t + ((size_t)l * GT + t) * 128 * 384, 384, 128);
      wtb_kernel<<<(128 * 128 + 255) / 256, 256, 0, stream>>>(
          pre_W2 + ((size_t)l * GT + t) * 128 * 128,
          preW2t + ((size_t)l * GT + t) * 128 * 128, 128, 128);
    }
  wtb_kernel<<<(128 * 256 + 255) / 256, 256, 0, stream>>>(fcu_W1, fcuW1t, 128, 256);
  wtb_kernel<<<(256 * 256 + 255) / 256, 256, 0, stream>>>(fcu_W2, fcuW2t, 256, 256);
  wtb_kernel<<<(128 * 256 + 255) / 256, 256, 0, stream>>>(fcv_W1, fcvW1t, 128, 256);
  wtb_kernel<<<(256 * 256 + 255) / 256, 256, 0, stream>>>(fcv_W2, fcvW2t, 256, 256);
  wtb_kernel<<<(256 * 256 + 255) / 256, 256, 0, stream>>>(fc_W1, fcW1t, 256, 256);
  wtb_kernel<<<(256 * 64 + 255) / 256, 256, 0, stream>>>(fc_W2, fcW2t, 256, 64);
  wtb_kernel<<<(128 * 128 + 255) / 256, 256, 0, stream>>>(eu_W1, euW1t, 128, 128);
  wtb_kernel<<<(128 * 64 + 255) / 256, 256, 0, stream>>>(eu_W2, euW2t, 128, 64);

  f2b_kernel<<<(N_ * 128 + 255) / 256, 256, 0, stream>>>(x_in, xb, N_ * 128);

  const float* x_cur = x_in;
  const float* ea_cur = ea_in;

  for (int l = 0; l < GL; ++l) {
    // ---- PNA conv ----
    agg_init_kernel<<<(N_ * 512 + 255) / 256, 256, 0, stream>>>(sumb, sumsqb, mxb, N_ * 512);
    for (int c = 0; c < nchunks; ++c) {
      long p0 = (long)c * Ec;
      int Mc = (int)(((long)E_ - p0 < Ec) ? ((long)E_ - p0) : Ec);
      // enc chunk (gathered via eidx) -> Acat cols 256..383 (bf16 out)
      {
        dim3 g(2, (Mc + 63) / 64);
        gemm_k<false, true, true><<<g, 256, 0, stream>>>(
            ea_cur, eidx + p0, enc_W + (size_t)l * 64 * 128, enc_b + (size_t)l * 128,
            Acatb + 256, Mc, 128, 64, 64, 128, 384);
      }
      build_acat_kernel<<<(Mc * 32 + 255) / 256, 256, 0, stream>>>(
          xb, eidx, src, dst, p0, Mc, Acatb);
      for (int t = 0; t < GT; ++t) {
        dim3 gh_(128 / 64, Mc / 64);
        mgemm_k<true, false, false, true><<<gh_, 256, 0, stream>>>(
            Acatb, nullptr, nullptr,
            preW1t + ((size_t)l * GT + t) * 128 * 384,
            pre_b1 + ((size_t)l * GT + t) * 128,
            hb, Mc, 128, 384, 384, 128);
        mgemm_k<false, false, false, false><<<gh_, 256, 0, stream>>>(
            hb, nullptr, nullptr,
            preW2t + ((size_t)l * GT + t) * 128 * 128,
            pre_b2 + ((size_t)l * GT + t) * 128,
            msgf, Mc, 128, 128, 128, 128);
        agg_merge_kernel<<<Mc / 64, 128, 0, stream>>>(
            msgf, eidx, dst, p0,
            sumb + (size_t)t * N_ * 128, sumsqb + (size_t)t * N_ * 128,
            mxb + (size_t)t * N_ * 128);
      }
    }
    for (int t = 0; t < GT; ++t) {
      finalize_kernel<<<(N_ * 128 + 255) / 256, 256, 0, stream>>>(
          sumb + (size_t)t * N_ * 128, sumsqb + (size_t)t * N_ * 128,
          mxb + (size_t)t * N_ * 128, rowptr, N_ * 128);
      cat_gemm_k<<<(N_ + 63) / 64, 256, 0, stream>>>(
          x_cur, sumb + (size_t)t * N_ * 128,
          (const float*)(mxb + (size_t)t * N_ * 128),
          sumsqb + (size_t)t * N_ * 128,
          post_W1 + ((size_t)l * GT + t) * 512 * 32,
          post_b1 + ((size_t)l * GT + t) * 32,
          q1 + t * 32, N_);
      dim3 g2(1, (N_ + 63) / 64);
      gemm_k<false, false, false><<<g2, 256, 0, stream>>>(
          q1 + t * 32, nullptr,
          post_W2 + ((size_t)l * GT + t) * 32 * 32,
          post_b2 + ((size_t)l * GT + t) * 32,
          q2 + t * 32, N_, 32, 32, 128, 32, 128);
    }
    {
      dim3 g((128 + 63) / 64, (N_ + 63) / 64);
      gemm_k<false, false, false><<<g, 256, 0, stream>>>(
          q2, nullptr, lin_W + (size_t)l * 128 * 128, lin_b + (size_t)l * 128,
          mb, N_, 128, 128, 128, 128, 128);
    }

    // ---- GRU ----
    {
      dim3 g((384 + 63) / 64, (N_ + 63) / 64);
      gemm_k<false, false, false><<<g, 256, 0, stream>>>(
          mb, nullptr, gru_Wi, gru_bi, gib, N_, 384, 128, 128, 384, 384);
      gemm_k<false, false, false><<<g, 256, 0, stream>>>(
          x_cur, nullptr, gru_Wh, gru_bh, ghb, N_, 384, 128, 128, 384, 384);
    }
    gru_kernel<<<(N_ * 128 + 255) / 256, 256, 0, stream>>>(gib, ghb, x_cur, Hb, N_ * 128);
    f2b_kernel<<<(N_ * 128 + 255) / 256, 256, 0, stream>>>(Hb, xb, N_ * 128);

    // ---- edge update (chunked, bf16 MFMA chain) ----
    for (int c = 0; c < nchunks; ++c) {
      long e0 = (long)c * Ec;
      int Mc = (int)(((long)E_ - e0 < Ec) ? ((long)E_ - e0) : Ec);
      dim3 g4(4, Mc / 64), g1(1, Mc / 64), g2(2, Mc / 64);
      // fu1 -> C1b
      mgemm_k<true, true, false, true><<<g4, 256, 0, stream>>>(
          xb, nullptr, src + e0, fcuW1t, fcu_b1, C1b, Mc, 256, 128, 128, 256);
      // fu2 -> C2b
      mgemm_k<true, false, false, true><<<g4, 256, 0, stream>>>(
          C1b, nullptr, nullptr, fcuW2t, fcu_b2, C2b, Mc, 256, 256, 256, 256);
      // fv1 -> C1b
      mgemm_k<true, true, false, true><<<g4, 256, 0, stream>>>(
          xb, nullptr, dst + e0, fcvW1t, fcv_b1, C1b, Mc, 256, 128, 128, 256);
      // fv2 -> C3b
      mgemm_k<true, false, false, true><<<g4, 256, 0, stream>>>(
          C1b, nullptr, nullptr, fcvW2t, fcv_b2, C3b, Mc, 256, 256, 256, 256);
      // fc1 = relu((fu2 .* fv2) @ fc_W1 + b) -> C1b
      mgemm_k<true, false, true, true><<<g4, 256, 0, stream>>>(
          C2b, C3b, nullptr, fcW1t, fc_b1, C1b, Mc, 256, 256, 256, 256);
      // med -> C2b (Mc x 64)
      mgemm_k<true, false, false, true><<<g1, 256, 0, stream>>>(
          C1b, nullptr, nullptr, fcW2t, fc_b2, C2b, Mc, 64, 256, 256, 64);
      // ecat = [med | bf16(ea)] -> C3b (Mc x 128)
      concat_b_kernel<<<(int)(((long)Mc * 128 + 255) / 256), 256, 0, stream>>>(
          C2b, ea_cur + e0 * 64, C3b, (long)Mc * 128);
      // eu1 -> C1b (Mc x 128)
      mgemm_k<true, false, false, true><<<g2, 256, 0, stream>>>(
          C3b, nullptr, nullptr, euW1t, eu_b1, C1b, Mc, 128, 128, 128, 128);
      // ea_next -> EAp (fp32)
      mgemm_k<false, false, false, false><<<g1, 256, 0, stream>>>(
          C1b, nullptr, nullptr, euW2t, eu_b2, EAp + e0 * 64, Mc, 64, 128, 128, 64);
    }

    x_cur = Hb;
    ea_cur = EAp;
  }

  // outputs: [out (N*128) | ea (in place) | out (N*128)]
  hipMemcpyAsync(out, x_cur, (size_t)N_ * 128 * 4, hipMemcpyDeviceToDevice, stream);
  hipMemcpyAsync(out + (size_t)N_ * 128 + (size_t)E_ * 64, x_cur,
                 (size_t)N_ * 128 * 4, hipMemcpyDeviceToDevice, stream);
}

// Round 5
// 3901.534 us; speedup vs baseline: 4.8751x; 1.1323x over previous
//
#include <hip/hip_runtime.h>
#include <hip/hip_bf16.h>
#include <math.h>

#define GN 10000
#define GNP 10048        // GN padded to 64
#define GE 160000
#define GT 4
#define GL 3

typedef __attribute__((ext_vector_type(8))) short short8;
typedef __attribute__((ext_vector_type(4))) float f32x4;
typedef unsigned short u16;

__device__ __forceinline__ u16 f2b(float f) {
  unsigned u = __float_as_uint(f);
  unsigned r = (u + 0x7FFFu + ((u >> 16) & 1u)) >> 16;
  return (u16)r;
}
__device__ __forceinline__ float b2f(u16 b) {
  return __uint_as_float(((unsigned)b) << 16);
}

// ---------------------------------------------------------------------------
// fp32 tiled GEMM (only the tiny 32x32 post-W2 uses this now)
// ---------------------------------------------------------------------------
template<bool RELU_C, bool GATHER, bool OUTB>
__global__ __launch_bounds__(256) void gemm_k(
    const float* __restrict__ A, const int* __restrict__ idx,
    const float* __restrict__ B, const float* __restrict__ bias,
    void* __restrict__ Cv,
    int M, int N, int K, int lda, int ldb, int ldc)
{
  __shared__ float As[16][65];
  __shared__ float Bs[16][65];
  const int tid = threadIdx.x;
  const int brow = blockIdx.y * 64, bcol = blockIdx.x * 64;
  const int tr = ((tid >> 4) & 15) << 2;
  const int tc = (tid & 15) << 2;
  float acc[4][4] = {{0.f}};

  for (int k0 = 0; k0 < K; k0 += 16) {
    for (int i = tid; i < 64 * 16; i += 256) {
      int r = i >> 4, c = i & 15;
      int gr = brow + r, gk = k0 + c;
      float v = 0.f;
      if (gr < M && gk < K) {
        size_t ar = GATHER ? (size_t)idx[gr] : (size_t)gr;
        v = A[ar * (size_t)lda + gk];
      }
      As[c][r] = v;
    }
    for (int i = tid; i < 16 * 64; i += 256) {
      int r = i >> 6, c = i & 63;
      int gk = k0 + r, gc = bcol + c;
      Bs[r][c] = (gk < K && gc < N) ? B[(size_t)gk * ldb + gc] : 0.f;
    }
    __syncthreads();
#pragma unroll
    for (int kk = 0; kk < 16; ++kk) {
      float a[4], b[4];
#pragma unroll
      for (int i = 0; i < 4; ++i) a[i] = As[kk][tr + i];
#pragma unroll
      for (int j = 0; j < 4; ++j) b[j] = Bs[kk][tc + j];
#pragma unroll
      for (int i = 0; i < 4; ++i)
#pragma unroll
        for (int j = 0; j < 4; ++j) acc[i][j] += a[i] * b[j];
    }
    __syncthreads();
  }

#pragma unroll
  for (int i = 0; i < 4; ++i) {
    int gr = brow + tr + i;
    if (gr >= M) continue;
#pragma unroll
    for (int j = 0; j < 4; ++j) {
      int gc = bcol + tc + j;
      if (gc >= N) continue;
      float v = acc[i][j] + bias[gc];
      if (RELU_C) v = fmaxf(v, 0.f);
      if (OUTB) ((u16*)Cv)[(size_t)gr * ldc + gc] = f2b(v);
      else      ((float*)Cv)[(size_t)gr * ldc + gc] = v;
    }
  }
}

// ---------------------------------------------------------------------------
// bf16 MFMA GEMM: C[M,N] = act( gather(A)[M,K] (.*A2) @ Bt^T + bias )
// A row-major bf16 (lda), Bt is [N][K] bf16. 64x64 tile, BK=64, 4 waves,
// mfma_f32_16x16x32_bf16, XOR-swizzled LDS. M%64==0, N%64==0, K%64==0.
// ---------------------------------------------------------------------------
template<bool RELU, bool GATHER, bool MUL, bool OUTB>
__global__ __launch_bounds__(256) void mgemm_k(
    const u16* __restrict__ A, const u16* __restrict__ A2,
    const int* __restrict__ idx,
    const u16* __restrict__ Bt, const float* __restrict__ bias,
    void* __restrict__ Cv,
    int M, int N, int K, int lda, int ldc)
{
  __shared__ u16 As[64 * 64];
  __shared__ u16 Bs[64 * 64];
  __shared__ int ridx[64];
  const int tid = threadIdx.x;
  const int brow = blockIdx.y * 64, bcol = blockIdx.x * 64;
  const int wid = tid >> 6, lane = tid & 63;
  const int wr = wid >> 1, wc = wid & 1;
  const int lrow = lane & 15, lk8 = (lane >> 4) * 8;

  if (tid < 64) ridx[tid] = GATHER ? idx[brow + tid] : (brow + tid);
  __syncthreads();

  f32x4 acc[2][2] = {};

  for (int k0 = 0; k0 < K; k0 += 64) {
#pragma unroll
    for (int s = 0; s < 2; ++s) {
      int c = tid + s * 256;
      int r = c >> 3, kq = (c & 7) * 8;
      const u16* sp = A + (size_t)ridx[r] * lda + k0 + kq;
      short8 v = *(const short8*)sp;
      if (MUL) {
        const u16* sp2 = A2 + (size_t)ridx[r] * lda + k0 + kq;
        short8 v2 = *(const short8*)sp2;
#pragma unroll
        for (int e = 0; e < 8; ++e)
          v[e] = (short)f2b(b2f((u16)v[e]) * b2f((u16)v2[e]));
      }
      int byt = (r * 128 + kq * 2) ^ ((r & 7) << 4);
      *(short8*)((char*)As + byt) = v;
    }
#pragma unroll
    for (int s = 0; s < 2; ++s) {
      int c = tid + s * 256;
      int r = c >> 3, kq = (c & 7) * 8;
      const u16* sp = Bt + (size_t)(bcol + r) * K + k0 + kq;
      short8 v = *(const short8*)sp;
      int byt = (r * 128 + kq * 2) ^ ((r & 7) << 4);
      *(short8*)((char*)Bs + byt) = v;
    }
    __syncthreads();
#pragma unroll
    for (int ks = 0; ks < 2; ++ks) {
      short8 a[2], b[2];
#pragma unroll
      for (int m = 0; m < 2; ++m) {
        int r = wr * 32 + m * 16 + lrow;
        int kk = ks * 32 + lk8;
        int byt = (r * 128 + kk * 2) ^ ((r & 7) << 4);
        a[m] = *(const short8*)((const char*)As + byt);
      }
#pragma unroll
      for (int n = 0; n < 2; ++n) {
        int r = wc * 32 + n * 16 + lrow;
        int kk = ks * 32 + lk8;
        int byt = (r * 128 + kk * 2) ^ ((r & 7) << 4);
        b[n] = *(const short8*)((const char*)Bs + byt);
      }
#pragma unroll
      for (int m = 0; m < 2; ++m)
#pragma unroll
        for (int n = 0; n < 2; ++n)
          acc[m][n] = __builtin_amdgcn_mfma_f32_16x16x32_bf16(a[m], b[n], acc[m][n], 0, 0, 0);
    }
    __syncthreads();
  }

#pragma unroll
  for (int m = 0; m < 2; ++m)
#pragma unroll
    for (int n = 0; n < 2; ++n) {
      int col = bcol + wc * 32 + n * 16 + (lane & 15);
      float bv = bias[col];
#pragma unroll
      for (int j = 0; j < 4; ++j) {
        int row = brow + wr * 32 + m * 16 + (lane >> 4) * 4 + j;
        float v = acc[m][n][j] + bv;
        if (RELU) v = fmaxf(v, 0.f);
        if (OUTB) ((u16*)Cv)[(size_t)row * ldc + col] = f2b(v);
        else      ((float*)Cv)[(size_t)row * ldc + col] = v;
      }
    }
}

// ---------------------------------------------------------------------------
// Edge sort by dst (counting sort)
// ---------------------------------------------------------------------------
__global__ void deg_kernel(const int* __restrict__ dst, int* __restrict__ deg, int E)
{
  int e = blockIdx.x * blockDim.x + threadIdx.x;
  if (e < E) atomicAdd(&deg[dst[e]], 1);
}

__global__ void scan_kernel(const int* __restrict__ deg, int* __restrict__ rowptr, int n)
{
  __shared__ int tmp[256];
  __shared__ int carry;
  if (threadIdx.x == 0) carry = 0;
  __syncthreads();
  for (int base = 0; base < n; base += 256) {
    int i = base + (int)threadIdx.x;
    int v = (i < n) ? deg[i] : 0;
    tmp[threadIdx.x] = v;
    __syncthreads();
    for (int off = 1; off < 256; off <<= 1) {
      int t = (threadIdx.x >= (unsigned)off) ? tmp[threadIdx.x - off] : 0;
      __syncthreads();
      tmp[threadIdx.x] += t;
      __syncthreads();
    }
    if (i < n) rowptr[i] = carry + tmp[threadIdx.x] - v;
    __syncthreads();
    if (threadIdx.x == 0) carry += tmp[255];
    __syncthreads();
  }
  if (threadIdx.x == 0) rowptr[n] = carry;
}

__global__ void scatter_kernel(const int* __restrict__ dst, int* __restrict__ cursor,
                               int* __restrict__ eidx, int E)
{
  int e = blockIdx.x * blockDim.x + threadIdx.x;
  if (e < E) {
    int p = atomicAdd(&cursor[dst[e]], 1);
    eidx[p] = e;
  }
}

// ---------------------------------------------------------------------------
// Batched weight transpose+convert: W[b] (K x N fp32) -> Wt[b] (N x K bf16)
// Wt block stride = wtStride elements (>= N*K, for padded layouts).
// ---------------------------------------------------------------------------
__global__ void wtb_kernel(const float* __restrict__ W, u16* __restrict__ Wt,
                           int K, int N, size_t wtStride)
{
  int b = blockIdx.y;
  const float* Wb = W + (size_t)b * K * N;
  u16* Wtb = Wt + (size_t)b * wtStride;
  for (int i = blockIdx.x * blockDim.x + threadIdx.x; i < K * N;
       i += gridDim.x * blockDim.x) {
    int k = i / N, n = i % N;
    Wtb[(size_t)n * K + k] = f2b(Wb[i]);
  }
}

// bias pad: postb1p[(b)*64 + j] = post_b1[b*32 + j] for j<32 (rest stays 0)
__global__ void biaspad_kernel(const float* __restrict__ b32, float* __restrict__ b64, int total)
{
  int i = blockIdx.x * blockDim.x + threadIdx.x;
  if (i >= total) return;
  b64[(i / 32) * 64 + (i % 32)] = b32[i];
}

// fp32 -> bf16 convert
__global__ void f2b_kernel(const float* __restrict__ in, u16* __restrict__ out, int n)
{
  int i = blockIdx.x * blockDim.x + threadIdx.x;
  if (i < n) out[i] = f2b(in[i]);
}

// ---------------------------------------------------------------------------
// Build Acat (bf16) cols 0..255 for a chunk (sorted order): [xb[dst] | xb[src]]
// ---------------------------------------------------------------------------
__global__ void build_acat_kernel(const u16* __restrict__ xb,
                                  const int* __restrict__ eidx,
                                  const int* __restrict__ srcA,
                                  const int* __restrict__ dstA,
                                  long base, int Mc, u16* __restrict__ Acat)
{
  int i = blockIdx.x * blockDim.x + threadIdx.x;
  int total = Mc * 32;
  if (i >= total) return;
  int p = i >> 5, q = i & 31;
  int e = eidx[base + p];
  int c0 = q * 8;
  const u16* sp = (c0 < 128) ? (xb + (size_t)dstA[e] * 128 + c0)
                             : (xb + (size_t)srcA[e] * 128 + (c0 - 128));
  *(int4*)(Acat + (size_t)p * 384 + c0) = *(const int4*)sp;
}

// ---------------------------------------------------------------------------
// Aggregator init: sum=0, sumsq=0, mx=encode(-inf)
// ---------------------------------------------------------------------------
__global__ void agg_init_kernel(float* __restrict__ s, float* __restrict__ ss,
                                unsigned* __restrict__ mx, int total)
{
  int i = blockIdx.x * blockDim.x + threadIdx.x;
  if (i >= total) return;
  s[i] = 0.f; ss[i] = 0.f; mx[i] = 0x007FFFFFu;
}

// ---------------------------------------------------------------------------
// Sorted-segment merge of a chunk's msg (fp32, Mc x 128) into per-node accums
// ---------------------------------------------------------------------------
__global__ __launch_bounds__(128) void agg_merge_kernel(
    const float* __restrict__ msg, const int* __restrict__ eidx,
    const int* __restrict__ dst, long base,
    float* __restrict__ sumb, float* __restrict__ sumsqb,
    unsigned* __restrict__ mxb)
{
  __shared__ int nid[64];
  const int tid = threadIdx.x;
  const long p0 = (long)blockIdx.x * 64;
  if (tid < 64) nid[tid] = dst[eidx[base + p0 + tid]];
  __syncthreads();
  int col = tid;
  int cur = nid[0];
  float s = 0.f, ssq = 0.f, m = -INFINITY;
  for (int rr = 0; rr < 64; ++rr) {
    int n = nid[rr];
    if (n != cur) {
      size_t o = (size_t)cur * 128 + col;
      atomicAdd(&sumb[o], s);
      atomicAdd(&sumsqb[o], ssq);
      unsigned ub = __float_as_uint(m);
      atomicMax(&mxb[o], (ub & 0x80000000u) ? ~ub : (ub | 0x80000000u));
      cur = n; s = 0.f; ssq = 0.f; m = -INFINITY;
    }
    float v = msg[(size_t)(p0 + rr) * 128 + col];
    s += v; ssq += v * v; m = fmaxf(m, v);
  }
  size_t o = (size_t)cur * 128 + col;
  atomicAdd(&sumb[o], s);
  atomicAdd(&sumsqb[o], ssq);
  unsigned ub = __float_as_uint(m);
  atomicMax(&mxb[o], (ub & 0x80000000u) ? ~ub : (ub | 0x80000000u));
}

// ---------------------------------------------------------------------------
// Finalize (per tower): write bf16 cat tile [x | mean | max | std] (N x 512)
// ---------------------------------------------------------------------------
__global__ void finalize_kernel(
    const float* __restrict__ sumb, const float* __restrict__ sumsqb,
    const unsigned* __restrict__ mxb, const int* __restrict__ rowptr,
    const float* __restrict__ x, u16* __restrict__ catb, int total)
{
  int i = blockIdx.x * blockDim.x + threadIdx.x;
  if (i >= total) return;               // total = N*128
  int n = i >> 7, c = i & 127;
  float cnt = fmaxf((float)(rowptr[n + 1] - rowptr[n]), 1.f);
  float mean = sumb[i] / cnt;
  float msq  = sumsqb[i] / cnt;
  float sd = sqrtf(fmaxf(msq - mean * mean, 0.f) + 1e-5f);
  unsigned u = mxb[i];
  unsigned bits = (u & 0x80000000u) ? (u & 0x7FFFFFFFu) : ~u;
  float mxv = __uint_as_float(bits);
  if ((bits & 0x7F800000u) == 0x7F800000u) mxv = 0.f;
  u16* cb = catb + (size_t)n * 512;
  cb[c]       = f2b(x[(size_t)n * 128 + c]);
  cb[128 + c] = f2b(mean);
  cb[256 + c] = f2b(mxv);
  cb[384 + c] = f2b(sd);
}

// ---------------------------------------------------------------------------
// GRU elementwise combine (in-place safe)
// ---------------------------------------------------------------------------
__global__ void gru_kernel(const float* __restrict__ gi, const float* __restrict__ gh,
                           const float* __restrict__ h, float* __restrict__ hout, int total)
{
  int i = blockIdx.x * blockDim.x + threadIdx.x;
  if (i >= total) return;
  int n = i >> 7, c = i & 127;
  const float* gin = gi + (size_t)n * 384;
  const float* ghn = gh + (size_t)n * 384;
  float ir = gin[c], iz = gin[128 + c], inn = gin[256 + c];
  float hr = ghn[c], hz = ghn[128 + c], hn = ghn[256 + c];
  float r = 1.f / (1.f + __expf(-(ir + hr)));
  float z = 1.f / (1.f + __expf(-(iz + hz)));
  float nn = tanhf(inn + r * hn);
  hout[i] = (1.f - z) * nn + z * h[i];
}

// ---------------------------------------------------------------------------
// ecat = [med bf16 (M,64) | bf16(ea fp32) (M,64)] -> out bf16 (M,128)
// ---------------------------------------------------------------------------
__global__ void concat_b_kernel(const u16* __restrict__ med, const float* __restrict__ ea,
                                u16* __restrict__ out, long total)
{
  long i = (long)blockIdx.x * blockDim.x + threadIdx.x;
  if (i >= total) return;
  long e = i >> 7;
  int c = (int)(i & 127);
  out[i] = (c < 64) ? med[e * 64 + c] : f2b(ea[e * 64 + (c - 64)]);
}

// ---------------------------------------------------------------------------
extern "C" void kernel_launch(void* const* d_in, const int* in_sizes, int n_in,
                              void* d_out, int out_size, void* d_ws, size_t ws_size,
                              hipStream_t stream)
{
  const int N_ = GN, E_ = GE, Np = GNP;

  const float* x_in   = (const float*)d_in[0];
  const int*   src    = (const int*)d_in[1];
  const int*   dst    = src + E_;
  const float* ea_in  = (const float*)d_in[2];
  const float* enc_W  = (const float*)d_in[3];
  const float* enc_b  = (const float*)d_in[4];
  const float* pre_W1 = (const float*)d_in[5];
  const float* pre_b1 = (const float*)d_in[6];
  const float* pre_W2 = (const float*)d_in[7];
  const float* pre_b2 = (const float*)d_in[8];
  const float* post_W1 = (const float*)d_in[9];
  const float* post_b1 = (const float*)d_in[10];
  const float* post_W2 = (const float*)d_in[11];
  const float* post_b2 = (const float*)d_in[12];
  const float* lin_W  = (const float*)d_in[13];
  const float* lin_b  = (const float*)d_in[14];
  const float* gru_Wi = (const float*)d_in[15];
  const float* gru_Wh = (const float*)d_in[16];
  const float* gru_bi = (const float*)d_in[17];
  const float* gru_bh = (const float*)d_in[18];
  const float* fcu_W1 = (const float*)d_in[19];
  const float* fcu_b1 = (const float*)d_in[20];
  const float* fcu_W2 = (const float*)d_in[21];
  const float* fcu_b2 = (const float*)d_in[22];
  const float* fcv_W1 = (const float*)d_in[23];
  const float* fcv_b1 = (const float*)d_in[24];
  const float* fcv_W2 = (const float*)d_in[25];
  const float* fcv_b2 = (const float*)d_in[26];
  const float* fc_W1  = (const float*)d_in[27];
  const float* fc_b1  = (const float*)d_in[28];
  const float* fc_W2  = (const float*)d_in[29];
  const float* fc_b2  = (const float*)d_in[30];
  const float* eu_W1  = (const float*)d_in[31];
  const float* eu_b1  = (const float*)d_in[32];
  const float* eu_W2  = (const float*)d_in[33];
  const float* eu_b2  = (const float*)d_in[34];

  // ---- workspace arena ----
  size_t used = 0;
  char* w = (char*)d_ws;
  auto alloc = [&](size_t bytes) {
    char* p = w + used;
    used += (bytes + 255) & ~(size_t)255;
    return p;
  };
  float*    sumb   = (float*)alloc((size_t)N_ * 512 * 4);   // [t][n][128]
  float*    sumsqb = (float*)alloc((size_t)N_ * 512 * 4);
  unsigned* mxb    = (unsigned*)alloc((size_t)N_ * 512 * 4);
  float*    q1   = (float*)alloc((size_t)Np * 64 * 4);      // per-tower post1 out
  u16*      q2b  = (u16*)alloc((size_t)Np * 128 * 2);
  u16*      mbb  = (u16*)alloc((size_t)Np * 128 * 2);
  float*    gib  = (float*)alloc((size_t)Np * 384 * 4);
  float*    ghb  = (float*)alloc((size_t)Np * 384 * 4);
  float*    Hb   = (float*)alloc((size_t)N_ * 128 * 4);
  u16*      xb   = (u16*)alloc((size_t)Np * 128 * 2);
  u16*      catb = (u16*)alloc((size_t)Np * 512 * 2);
  u16*      eab  = (u16*)alloc((size_t)E_ * 64 * 2);
  // bf16 transposed weights
  u16* encWt  = (u16*)alloc((size_t)GL * 128 * 64 * 2);
  u16* preW1t = (u16*)alloc((size_t)GL * GT * 128 * 384 * 2);
  u16* preW2t = (u16*)alloc((size_t)GL * GT * 128 * 128 * 2);
  u16* postW1t = (u16*)alloc((size_t)GL * GT * 64 * 512 * 2);  // padded 32->64
  float* postb1p = (float*)alloc((size_t)GL * GT * 64 * 4);
  u16* linWt  = (u16*)alloc((size_t)GL * 128 * 128 * 2);
  u16* gruWit = (u16*)alloc((size_t)384 * 128 * 2);
  u16* gruWht = (u16*)alloc((size_t)384 * 128 * 2);
  u16* fcuW1t = (u16*)alloc((size_t)256 * 128 * 2);
  u16* fcuW2t = (u16*)alloc((size_t)256 * 256 * 2);
  u16* fcvW1t = (u16*)alloc((size_t)256 * 128 * 2);
  u16* fcvW2t = (u16*)alloc((size_t)256 * 256 * 2);
  u16* fcW1t  = (u16*)alloc((size_t)256 * 256 * 2);
  u16* fcW2t  = (u16*)alloc((size_t)64 * 256 * 2);
  u16* euW1t  = (u16*)alloc((size_t)128 * 128 * 2);
  u16* euW2t  = (u16*)alloc((size_t)64 * 128 * 2);
  int* eidx   = (int*)alloc((size_t)E_ * 4);
  int* degb   = (int*)alloc((size_t)(N_ + 1) * 4);
  int* rowptr = (int*)alloc((size_t)(N_ + 1) * 4);
  int* cursor = (int*)alloc((size_t)(N_ + 1) * 4);

  // chunk arena: 1792 B/row (conv: Acat 768 + hb_all 1024; edge: 3 x 512)
  size_t avail = (ws_size > used + 4096) ? (ws_size - used - 4096) : 0;
  long Ec = (long)(avail / 1792);
  if (Ec > E_) Ec = E_;
  Ec &= ~255L;
  if (Ec < 256) return;   // ws too small: fail cleanly
  char* arena = alloc((size_t)Ec * 1792);
  if (used > ws_size) return;
  const int nchunks = (int)((E_ + Ec - 1) / Ec);
  // conv-phase layout
  u16*   Acatb = (u16*)arena;                         // Ec x 384 bf16
  u16*   hball = (u16*)(arena + (size_t)Ec * 768);    // Ec x 512 bf16
  float* msgf  = (float*)arena;                       // Ec x 128 f32 (reuses Acat)
  // edge-phase layout
  u16* C1b = (u16*)arena;
  u16* C2b = (u16*)(arena + (size_t)Ec * 512);
  u16* C3b = (u16*)(arena + (size_t)Ec * 1024);

  float* out = (float*)d_out;
  float* EAp = out + (size_t)N_ * 128;   // ea state lives in d_out

  // ---- one-time setup ----
  hipMemsetAsync(degb, 0, (size_t)N_ * 4, stream);
  deg_kernel<<<(E_ + 255) / 256, 256, 0, stream>>>(dst, degb, E_);
  scan_kernel<<<1, 256, 0, stream>>>(degb, rowptr, N_);
  hipMemcpyAsync(cursor, rowptr, (size_t)N_ * 4, hipMemcpyDeviceToDevice, stream);
  scatter_kernel<<<(E_ + 255) / 256, 256, 0, stream>>>(dst, cursor, eidx, E_);

  hipMemsetAsync(postW1t, 0, (size_t)GL * GT * 64 * 512 * 2, stream);
  hipMemsetAsync(postb1p, 0, (size_t)GL * GT * 64 * 4, stream);
  {
    dim3 gb(48, GL);
    wtb_kernel<<<gb, 256, 0, stream>>>(enc_W, encWt, 64, 128, 128 * 64);
    wtb_kernel<<<gb, 256, 0, stream>>>(lin_W, linWt, 128, 128, 128 * 128);
    dim3 gt(48, GL * GT);
    wtb_kernel<<<gt, 256, 0, stream>>>(pre_W1, preW1t, 384, 128, 128 * 384);
    wtb_kernel<<<gt, 256, 0, stream>>>(pre_W2, preW2t, 128, 128, 128 * 128);
    wtb_kernel<<<gt, 256, 0, stream>>>(post_W1, postW1t, 512, 32, 64 * 512);
    dim3 g1(48, 1);
    wtb_kernel<<<g1, 256, 0, stream>>>(gru_Wi, gruWit, 128, 384, 384 * 128);
    wtb_kernel<<<g1, 256, 0, stream>>>(gru_Wh, gruWht, 128, 384, 384 * 128);
    wtb_kernel<<<g1, 256, 0, stream>>>(fcu_W1, fcuW1t, 128, 256, 256 * 128);
    wtb_kernel<<<g1, 256, 0, stream>>>(fcu_W2, fcuW2t, 256, 256, 256 * 256);
    wtb_kernel<<<g1, 256, 0, stream>>>(fcv_W1, fcvW1t, 128, 256, 256 * 128);
    wtb_kernel<<<g1, 256, 0, stream>>>(fcv_W2, fcvW2t, 256, 256, 256 * 256);
    wtb_kernel<<<g1, 256, 0, stream>>>(fc_W1, fcW1t, 256, 256, 256 * 256);
    wtb_kernel<<<g1, 256, 0, stream>>>(fc_W2, fcW2t, 256, 64, 64 * 256);
    wtb_kernel<<<g1, 256, 0, stream>>>(eu_W1, euW1t, 128, 128, 128 * 128);
    wtb_kernel<<<g1, 256, 0, stream>>>(eu_W2, euW2t, 128, 64, 64 * 128);
  }
  biaspad_kernel<<<(GL * GT * 32 + 255) / 256, 256, 0, stream>>>(
      post_b1, postb1p, GL * GT * 32);

  f2b_kernel<<<(N_ * 128 + 255) / 256, 256, 0, stream>>>(x_in, xb, N_ * 128);
  f2b_kernel<<<(E_ * 64 + 255) / 256, 256, 0, stream>>>(ea_in, eab, E_ * 64);

  const float* x_cur = x_in;
  const float* ea_cur = ea_in;

  for (int l = 0; l < GL; ++l) {
    // ---- PNA conv ----
    agg_init_kernel<<<(N_ * 512 + 255) / 256, 256, 0, stream>>>(sumb, sumsqb, mxb, N_ * 512);
    for (int c = 0; c < nchunks; ++c) {
      long p0 = (long)c * Ec;
      int Mc = (int)(((long)E_ - p0 < Ec) ? ((long)E_ - p0) : Ec);
      dim3 gEnc(2, Mc / 64), gH(8, Mc / 64), gMsg(2, Mc / 64);
      // enc chunk (gathered bf16) -> Acat cols 256..383
      mgemm_k<false, true, false, true><<<gEnc, 256, 0, stream>>>(
          eab, nullptr, eidx + p0, encWt + (size_t)l * 128 * 64,
          enc_b + (size_t)l * 128, Acatb + 256, Mc, 128, 64, 64, 384);
      build_acat_kernel<<<(Mc * 32 + 255) / 256, 256, 0, stream>>>(
          xb, eidx, src, dst, p0, Mc, Acatb);
      // h (all towers): Mc x 512, K=384
      mgemm_k<true, false, false, true><<<gH, 256, 0, stream>>>(
          Acatb, nullptr, nullptr, preW1t + (size_t)l * 512 * 384,
          pre_b1 + (size_t)l * 512, hball, Mc, 512, 384, 384, 512);
      for (int t = 0; t < GT; ++t) {
        mgemm_k<false, false, false, false><<<gMsg, 256, 0, stream>>>(
            hball + t * 128, nullptr, nullptr,
            preW2t + ((size_t)l * GT + t) * 128 * 128,
            pre_b2 + (size_t)l * 512 + t * 128,
            msgf, Mc, 128, 128, 512, 128);
        agg_merge_kernel<<<Mc / 64, 128, 0, stream>>>(
            msgf, eidx, dst, p0,
            sumb + (size_t)t * N_ * 128, sumsqb + (size_t)t * N_ * 128,
            mxb + (size_t)t * N_ * 128);
      }
    }
    for (int t = 0; t < GT; ++t) {
      finalize_kernel<<<(N_ * 128 + 255) / 256, 256, 0, stream>>>(
          sumb + (size_t)t * N_ * 128, sumsqb + (size_t)t * N_ * 128,
          mxb + (size_t)t * N_ * 128, rowptr, x_cur, catb, N_ * 128);
      dim3 gP1(1, Np / 64);
      mgemm_k<true, false, false, false><<<gP1, 256, 0, stream>>>(
          catb, nullptr, nullptr, postW1t + ((size_t)l * GT + t) * 64 * 512,
          postb1p + ((size_t)l * GT + t) * 64, q1, Np, 64, 512, 512, 64);
      dim3 gP2(1, (N_ + 63) / 64);
      gemm_k<false, false, true><<<gP2, 256, 0, stream>>>(
          q1, nullptr, post_W2 + ((size_t)l * GT + t) * 32 * 32,
          post_b2 + ((size_t)l * GT + t) * 32,
          q2b + t * 32, N_, 32, 32, 64, 32, 128);
    }
    {
      dim3 gL(2, Np / 64), gG(6, Np / 64);
      mgemm_k<false, false, false, true><<<gL, 256, 0, stream>>>(
          q2b, nullptr, nullptr, linWt + (size_t)l * 128 * 128,
          lin_b + (size_t)l * 128, mbb, Np, 128, 128, 128, 128);
      mgemm_k<false, false, false, false><<<gG, 256, 0, stream>>>(
          mbb, nullptr, nullptr, gruWit, gru_bi, gib, Np, 384, 128, 128, 384);
      mgemm_k<false, false, false, false><<<gG, 256, 0, stream>>>(
          xb, nullptr, nullptr, gruWht, gru_bh, ghb, Np, 384, 128, 128, 384);
    }
    gru_kernel<<<(N_ * 128 + 255) / 256, 256, 0, stream>>>(gib, ghb, x_cur, Hb, N_ * 128);
    f2b_kernel<<<(N_ * 128 + 255) / 256, 256, 0, stream>>>(Hb, xb, N_ * 128);

    // ---- edge update (chunked, bf16 MFMA chain) ----
    for (int c = 0; c < nchunks; ++c) {
      long e0 = (long)c * Ec;
      int Mc = (int)(((long)E_ - e0 < Ec) ? ((long)E_ - e0) : Ec);
      dim3 g4(4, Mc / 64), g1(1, Mc / 64), g2(2, Mc / 64);
      mgemm_k<true, true, false, true><<<g4, 256, 0, stream>>>(
          xb, nullptr, src + e0, fcuW1t, fcu_b1, C1b, Mc, 256, 128, 128, 256);
      mgemm_k<true, false, false, true><<<g4, 256, 0, stream>>>(
          C1b, nullptr, nullptr, fcuW2t, fcu_b2, C2b, Mc, 256, 256, 256, 256);
      mgemm_k<true, true, false, true><<<g4, 256, 0, stream>>>(
          xb, nullptr, dst + e0, fcvW1t, fcv_b1, C1b, Mc, 256, 128, 128, 256);
      mgemm_k<true, false, false, true><<<g4, 256, 0, stream>>>(
          C1b, nullptr, nullptr, fcvW2t, fcv_b2, C3b, Mc, 256, 256, 256, 256);
      mgemm_k<true, false, true, true><<<g4, 256, 0, stream>>>(
          C2b, C3b, nullptr, fcW1t, fc_b1, C1b, Mc, 256, 256, 256, 256);
      mgemm_k<true, false, false, true><<<g1, 256, 0, stream>>>(
          C1b, nullptr, nullptr, fcW2t, fc_b2, C2b, Mc, 64, 256, 256, 64);
      concat_b_kernel<<<(int)(((long)Mc * 128 + 255) / 256), 256, 0, stream>>>(
          C2b, ea_cur + e0 * 64, C3b, (long)Mc * 128);
      mgemm_k<true, false, false, true><<<g2, 256, 0, stream>>>(
          C3b, nullptr, nullptr, euW1t, eu_b1, C1b, Mc, 128, 128, 128, 128);
      mgemm_k<false, false, false, false><<<g1, 256, 0, stream>>>(
          C1b, nullptr, nullptr, euW2t, eu_b2, EAp + e0 * 64, Mc, 64, 128, 128, 64);
    }
    f2b_kernel<<<(E_ * 64 + 255) / 256, 256, 0, stream>>>(EAp, eab, E_ * 64);

    x_cur = Hb;
    ea_cur = EAp;
  }

  // outputs: [out (N*128) | ea (in place) | out (N*128)]
  hipMemcpyAsync(out, x_cur, (size_t)N_ * 128 * 4, hipMemcpyDeviceToDevice, stream);
  hipMemcpyAsync(out + (size_t)N_ * 128 + (size_t)E_ * 64, x_cur,
                 (size_t)N_ * 128 * 4, hipMemcpyDeviceToDevice, stream);
}

// Round 6
// 3094.905 us; speedup vs baseline: 6.1457x; 1.2606x over previous
//
#include <hip/hip_runtime.h>
#include <hip/hip_bf16.h>
#include <math.h>

#define GN 10000
#define GNP 10112        // GN padded to 128
#define GE 160000
#define GT 4
#define GL 3

typedef __attribute__((ext_vector_type(8))) short short8;
typedef __attribute__((ext_vector_type(4))) float f32x4;
typedef unsigned short u16;

__device__ __forceinline__ u16 f2b(float f) {
  unsigned u = __float_as_uint(f);
  unsigned r = (u + 0x7FFFu + ((u >> 16) & 1u)) >> 16;
  return (u16)r;
}
__device__ __forceinline__ float b2f(u16 b) {
  return __uint_as_float(((unsigned)b) << 16);
}

// ---------------------------------------------------------------------------
// fp32 tiled GEMM (only the tiny 32x32 post-W2 uses this)
// ---------------------------------------------------------------------------
template<bool RELU_C, bool GATHER, bool OUTB>
__global__ __launch_bounds__(256) void gemm_k(
    const float* __restrict__ A, const int* __restrict__ idx,
    const float* __restrict__ B, const float* __restrict__ bias,
    void* __restrict__ Cv,
    int M, int N, int K, int lda, int ldb, int ldc)
{
  __shared__ float As[16][65];
  __shared__ float Bs[16][65];
  const int tid = threadIdx.x;
  const int brow = blockIdx.y * 64, bcol = blockIdx.x * 64;
  const int tr = ((tid >> 4) & 15) << 2;
  const int tc = (tid & 15) << 2;
  float acc[4][4] = {{0.f}};

  for (int k0 = 0; k0 < K; k0 += 16) {
    for (int i = tid; i < 64 * 16; i += 256) {
      int r = i >> 4, c = i & 15;
      int gr = brow + r, gk = k0 + c;
      float v = 0.f;
      if (gr < M && gk < K) {
        size_t ar = GATHER ? (size_t)idx[gr] : (size_t)gr;
        v = A[ar * (size_t)lda + gk];
      }
      As[c][r] = v;
    }
    for (int i = tid; i < 16 * 64; i += 256) {
      int r = i >> 6, c = i & 63;
      int gk = k0 + r, gc = bcol + c;
      Bs[r][c] = (gk < K && gc < N) ? B[(size_t)gk * ldb + gc] : 0.f;
    }
    __syncthreads();
#pragma unroll
    for (int kk = 0; kk < 16; ++kk) {
      float a[4], b[4];
#pragma unroll
      for (int i = 0; i < 4; ++i) a[i] = As[kk][tr + i];
#pragma unroll
      for (int j = 0; j < 4; ++j) b[j] = Bs[kk][tc + j];
#pragma unroll
      for (int i = 0; i < 4; ++i)
#pragma unroll
        for (int j = 0; j < 4; ++j) acc[i][j] += a[i] * b[j];
    }
    __syncthreads();
  }

#pragma unroll
  for (int i = 0; i < 4; ++i) {
    int gr = brow + tr + i;
    if (gr >= M) continue;
#pragma unroll
    for (int j = 0; j < 4; ++j) {
      int gc = bcol + tc + j;
      if (gc >= N) continue;
      float v = acc[i][j] + bias[gc];
      if (RELU_C) v = fmaxf(v, 0.f);
      if (OUTB) ((u16*)Cv)[(size_t)gr * ldc + gc] = f2b(v);
      else      ((float*)Cv)[(size_t)gr * ldc + gc] = v;
    }
  }
}

// ---------------------------------------------------------------------------
// bf16 MFMA GEMM, 64x64 tile (kept for N=64 outputs: postW1 / med / eu2)
// ---------------------------------------------------------------------------
template<bool RELU, bool GATHER, bool MUL, bool OUTB>
__global__ __launch_bounds__(256) void mgemm_k(
    const u16* __restrict__ A, const u16* __restrict__ A2,
    const int* __restrict__ idx,
    const u16* __restrict__ Bt, const float* __restrict__ bias,
    void* __restrict__ Cv,
    int M, int N, int K, int lda, int ldc)
{
  __shared__ u16 As[64 * 64];
  __shared__ u16 Bs[64 * 64];
  __shared__ int ridx[64];
  const int tid = threadIdx.x;
  const int brow = blockIdx.y * 64, bcol = blockIdx.x * 64;
  const int wid = tid >> 6, lane = tid & 63;
  const int wr = wid >> 1, wc = wid & 1;
  const int lrow = lane & 15, lk8 = (lane >> 4) * 8;

  if (tid < 64) ridx[tid] = GATHER ? idx[brow + tid] : (brow + tid);
  __syncthreads();

  f32x4 acc[2][2] = {};

  for (int k0 = 0; k0 < K; k0 += 64) {
#pragma unroll
    for (int s = 0; s < 2; ++s) {
      int c = tid + s * 256;
      int r = c >> 3, kq = (c & 7) * 8;
      const u16* sp = A + (size_t)ridx[r] * lda + k0 + kq;
      short8 v = *(const short8*)sp;
      if (MUL) {
        const u16* sp2 = A2 + (size_t)ridx[r] * lda + k0 + kq;
        short8 v2 = *(const short8*)sp2;
#pragma unroll
        for (int e = 0; e < 8; ++e)
          v[e] = (short)f2b(b2f((u16)v[e]) * b2f((u16)v2[e]));
      }
      int byt = (r * 128 + kq * 2) ^ ((r & 7) << 4);
      *(short8*)((char*)As + byt) = v;
    }
#pragma unroll
    for (int s = 0; s < 2; ++s) {
      int c = tid + s * 256;
      int r = c >> 3, kq = (c & 7) * 8;
      const u16* sp = Bt + (size_t)(bcol + r) * K + k0 + kq;
      short8 v = *(const short8*)sp;
      int byt = (r * 128 + kq * 2) ^ ((r & 7) << 4);
      *(short8*)((char*)Bs + byt) = v;
    }
    __syncthreads();
#pragma unroll
    for (int ks = 0; ks < 2; ++ks) {
      short8 a[2], b[2];
#pragma unroll
      for (int m = 0; m < 2; ++m) {
        int r = wr * 32 + m * 16 + lrow;
        int kk = ks * 32 + lk8;
        int byt = (r * 128 + kk * 2) ^ ((r & 7) << 4);
        a[m] = *(const short8*)((const char*)As + byt);
      }
#pragma unroll
      for (int n = 0; n < 2; ++n) {
        int r = wc * 32 + n * 16 + lrow;
        int kk = ks * 32 + lk8;
        int byt = (r * 128 + kk * 2) ^ ((r & 7) << 4);
        b[n] = *(const short8*)((const char*)Bs + byt);
      }
#pragma unroll
      for (int m = 0; m < 2; ++m)
#pragma unroll
        for (int n = 0; n < 2; ++n)
          acc[m][n] = __builtin_amdgcn_mfma_f32_16x16x32_bf16(a[m], b[n], acc[m][n], 0, 0, 0);
    }
    __syncthreads();
  }

#pragma unroll
  for (int m = 0; m < 2; ++m)
#pragma unroll
    for (int n = 0; n < 2; ++n) {
      int col = bcol + wc * 32 + n * 16 + (lane & 15);
      float bv = bias[col];
#pragma unroll
      for (int j = 0; j < 4; ++j) {
        int row = brow + wr * 32 + m * 16 + (lane >> 4) * 4 + j;
        float v = acc[m][n][j] + bv;
        if (RELU) v = fmaxf(v, 0.f);
        if (OUTB) ((u16*)Cv)[(size_t)row * ldc + col] = f2b(v);
        else      ((float*)Cv)[(size_t)row * ldc + col] = v;
      }
    }
}

// ---------------------------------------------------------------------------
// bf16 MFMA GEMM, 128x128 tile, BK=64, 4 waves (2x2), 4x4 frags/wave.
// C[M,N] = act( gather(A)[M,K] (.*A2) @ Bt^T + bias ), Bt = [N][K] bf16.
// XOR-swizzled LDS (byte ^= (row&7)<<4). M%128==0, N%128==0, K%64==0.
// ---------------------------------------------------------------------------
template<bool RELU, bool GATHER, bool MUL, bool OUTB>
__global__ __launch_bounds__(256) void mg2_k(
    const u16* __restrict__ A, const u16* __restrict__ A2,
    const int* __restrict__ idx,
    const u16* __restrict__ Bt, const float* __restrict__ bias,
    void* __restrict__ Cv,
    int M, int N, int K, int lda, int ldc)
{
  __shared__ u16 As[128 * 64];
  __shared__ u16 Bs[128 * 64];
  __shared__ int ridx[128];
  const int tid = threadIdx.x;
  const int brow = blockIdx.y * 128, bcol = blockIdx.x * 128;
  const int wid = tid >> 6, lane = tid & 63;
  const int wr = wid >> 1, wc = wid & 1;          // 2x2 waves, 64x64 each
  const int lrow = lane & 15, lkg = lane >> 4;    // lkg 0..3

  if (GATHER) {
    if (tid < 128) ridx[tid] = idx[brow + tid];
    __syncthreads();
  }

  f32x4 acc[4][4] = {};

  for (int k0 = 0; k0 < K; k0 += 64) {
    // stage A: 128 rows x 64 k bf16, 4 rounds x 256 thr x 16B
#pragma unroll
    for (int s = 0; s < 4; ++s) {
      int i = tid + s * 256;            // 0..1023
      int r = i >> 3, kq = (i & 7) * 8; // row 0..127, k-elem offset
      size_t grow = GATHER ? (size_t)ridx[r] : (size_t)(brow + r);
      const u16* sp = A + grow * lda + k0 + kq;
      short8 v = *(const short8*)sp;
      if (MUL) {
        const u16* sp2 = A2 + grow * lda + k0 + kq;
        short8 v2 = *(const short8*)sp2;
#pragma unroll
        for (int e = 0; e < 8; ++e)
          v[e] = (short)f2b(b2f((u16)v[e]) * b2f((u16)v2[e]));
      }
      int byt = (r * 128 + kq * 2) ^ ((r & 7) << 4);
      *(short8*)((char*)As + byt) = v;
    }
    // stage B: 128 out-cols x 64 k
#pragma unroll
    for (int s = 0; s < 4; ++s) {
      int i = tid + s * 256;
      int r = i >> 3, kq = (i & 7) * 8;
      const u16* sp = Bt + (size_t)(bcol + r) * K + k0 + kq;
      short8 v = *(const short8*)sp;
      int byt = (r * 128 + kq * 2) ^ ((r & 7) << 4);
      *(short8*)((char*)Bs + byt) = v;
    }
    __syncthreads();
#pragma unroll
    for (int ks = 0; ks < 2; ++ks) {
      const int kb = ks * 64 + lkg * 16;          // byte offset of lane's 16B in k
      short8 a[4], b[4];
#pragma unroll
      for (int m = 0; m < 4; ++m) {
        int r = wr * 64 + m * 16 + lrow;
        int byt = (r * 128 + kb) ^ ((r & 7) << 4);
        a[m] = *(const short8*)((const char*)As + byt);
      }
#pragma unroll
      for (int n = 0; n < 4; ++n) {
        int r = wc * 64 + n * 16 + lrow;
        int byt = (r * 128 + kb) ^ ((r & 7) << 4);
        b[n] = *(const short8*)((const char*)Bs + byt);
      }
#pragma unroll
      for (int m = 0; m < 4; ++m)
#pragma unroll
        for (int n = 0; n < 4; ++n)
          acc[m][n] = __builtin_amdgcn_mfma_f32_16x16x32_bf16(a[m], b[n], acc[m][n], 0, 0, 0);
    }
    __syncthreads();
  }

#pragma unroll
  for (int m = 0; m < 4; ++m)
#pragma unroll
    for (int n = 0; n < 4; ++n) {
      int col = bcol + wc * 64 + n * 16 + lrow;
      float bv = bias[col];
#pragma unroll
      for (int j = 0; j < 4; ++j) {
        int row = brow + wr * 64 + m * 16 + lkg * 4 + j;
        float v = acc[m][n][j] + bv;
        if (RELU) v = fmaxf(v, 0.f);
        if (OUTB) ((u16*)Cv)[(size_t)row * ldc + col] = f2b(v);
        else      ((float*)Cv)[(size_t)row * ldc + col] = v;
      }
    }
}

// ---------------------------------------------------------------------------
// Edge sort by dst (counting sort)
// ---------------------------------------------------------------------------
__global__ void deg_kernel(const int* __restrict__ dst, int* __restrict__ deg, int E)
{
  int e = blockIdx.x * blockDim.x + threadIdx.x;
  if (e < E) atomicAdd(&deg[dst[e]], 1);
}

__global__ void scan_kernel(const int* __restrict__ deg, int* __restrict__ rowptr, int n)
{
  __shared__ int tmp[256];
  __shared__ int carry;
  if (threadIdx.x == 0) carry = 0;
  __syncthreads();
  for (int base = 0; base < n; base += 256) {
    int i = base + (int)threadIdx.x;
    int v = (i < n) ? deg[i] : 0;
    tmp[threadIdx.x] = v;
    __syncthreads();
    for (int off = 1; off < 256; off <<= 1) {
      int t = (threadIdx.x >= (unsigned)off) ? tmp[threadIdx.x - off] : 0;
      __syncthreads();
      tmp[threadIdx.x] += t;
      __syncthreads();
    }
    if (i < n) rowptr[i] = carry + tmp[threadIdx.x] - v;
    __syncthreads();
    if (threadIdx.x == 0) carry += tmp[255];
    __syncthreads();
  }
  if (threadIdx.x == 0) rowptr[n] = carry;
}

__global__ void scatter_kernel(const int* __restrict__ dst, int* __restrict__ cursor,
                               int* __restrict__ eidx, int E)
{
  int e = blockIdx.x * blockDim.x + threadIdx.x;
  if (e < E) {
    int p = atomicAdd(&cursor[dst[e]], 1);
    eidx[p] = e;
  }
}

// ---------------------------------------------------------------------------
// Batched weight transpose+convert: W[b] (K x N fp32) -> Wt[b] (N x K bf16)
// ---------------------------------------------------------------------------
__global__ void wtb_kernel(const float* __restrict__ W, u16* __restrict__ Wt,
                           int K, int N, size_t wtStride)
{
  int b = blockIdx.y;
  const float* Wb = W + (size_t)b * K * N;
  u16* Wtb = Wt + (size_t)b * wtStride;
  for (int i = blockIdx.x * blockDim.x + threadIdx.x; i < K * N;
       i += gridDim.x * blockDim.x) {
    int k = i / N, n = i % N;
    Wtb[(size_t)n * K + k] = f2b(Wb[i]);
  }
}

__global__ void biaspad_kernel(const float* __restrict__ b32, float* __restrict__ b64, int total)
{
  int i = blockIdx.x * blockDim.x + threadIdx.x;
  if (i >= total) return;
  b64[(i / 32) * 64 + (i % 32)] = b32[i];
}

__global__ void f2b_kernel(const float* __restrict__ in, u16* __restrict__ out, int n)
{
  int i = blockIdx.x * blockDim.x + threadIdx.x;
  if (i < n) out[i] = f2b(in[i]);
}

// ---------------------------------------------------------------------------
// Build Acat (bf16) cols 0..255 for a chunk (sorted order): [xb[dst] | xb[src]]
// ---------------------------------------------------------------------------
__global__ void build_acat_kernel(const u16* __restrict__ xb,
                                  const int* __restrict__ eidx,
                                  const int* __restrict__ srcA,
                                  const int* __restrict__ dstA,
                                  long base, int Mc, u16* __restrict__ Acat)
{
  int i = blockIdx.x * blockDim.x + threadIdx.x;
  int total = Mc * 32;
  if (i >= total) return;
  int p = i >> 5, q = i & 31;
  int e = eidx[base + p];
  int c0 = q * 8;
  const u16* sp = (c0 < 128) ? (xb + (size_t)dstA[e] * 128 + c0)
                             : (xb + (size_t)srcA[e] * 128 + (c0 - 128));
  *(int4*)(Acat + (size_t)p * 384 + c0) = *(const int4*)sp;
}

// ---------------------------------------------------------------------------
// Aggregator init
// ---------------------------------------------------------------------------
__global__ void agg_init_kernel(float* __restrict__ s, float* __restrict__ ss,
                                unsigned* __restrict__ mx, int total)
{
  int i = blockIdx.x * blockDim.x + threadIdx.x;
  if (i >= total) return;
  s[i] = 0.f; ss[i] = 0.f; mx[i] = 0x007FFFFFu;
}

// ---------------------------------------------------------------------------
// Sorted-segment merge (bf16 msg, all 4 towers via blockIdx.y)
// ---------------------------------------------------------------------------
__global__ __launch_bounds__(128) void agg_merge_kernel(
    const u16* __restrict__ msgb, size_t msgStride,
    const int* __restrict__ eidx, const int* __restrict__ dst, long base,
    float* __restrict__ sumb, float* __restrict__ sumsqb,
    unsigned* __restrict__ mxb, int Nn)
{
  __shared__ int nid[64];
  const int t = blockIdx.y;
  const u16* msg = msgb + (size_t)t * msgStride;
  float* sb = sumb + (size_t)t * Nn * 128;
  float* qb = sumsqb + (size_t)t * Nn * 128;
  unsigned* xb_ = mxb + (size_t)t * Nn * 128;
  const int tid = threadIdx.x;
  const long p0 = (long)blockIdx.x * 64;
  if (tid < 64) nid[tid] = dst[eidx[base + p0 + tid]];
  __syncthreads();
  int col = tid;
  int cur = nid[0];
  float s = 0.f, ssq = 0.f, m = -INFINITY;
  for (int rr = 0; rr < 64; ++rr) {
    int n = nid[rr];
    if (n != cur) {
      size_t o = (size_t)cur * 128 + col;
      atomicAdd(&sb[o], s);
      atomicAdd(&qb[o], ssq);
      unsigned ub = __float_as_uint(m);
      atomicMax(&xb_[o], (ub & 0x80000000u) ? ~ub : (ub | 0x80000000u));
      cur = n; s = 0.f; ssq = 0.f; m = -INFINITY;
    }
    float v = b2f(msg[(size_t)(p0 + rr) * 128 + col]);
    s += v; ssq += v * v; m = fmaxf(m, v);
  }
  size_t o = (size_t)cur * 128 + col;
  atomicAdd(&sb[o], s);
  atomicAdd(&qb[o], ssq);
  unsigned ub = __float_as_uint(m);
  atomicMax(&xb_[o], (ub & 0x80000000u) ? ~ub : (ub | 0x80000000u));
}

// ---------------------------------------------------------------------------
// Finalize (per tower): write bf16 cat tile [x | mean | max | std] (N x 512)
// ---------------------------------------------------------------------------
__global__ void finalize_kernel(
    const float* __restrict__ sumb, const float* __restrict__ sumsqb,
    const unsigned* __restrict__ mxb, const int* __restrict__ rowptr,
    const float* __restrict__ x, u16* __restrict__ catb, int total)
{
  int i = blockIdx.x * blockDim.x + threadIdx.x;
  if (i >= total) return;               // total = N*128
  int n = i >> 7, c = i & 127;
  float cnt = fmaxf((float)(rowptr[n + 1] - rowptr[n]), 1.f);
  float mean = sumb[i] / cnt;
  float msq  = sumsqb[i] / cnt;
  float sd = sqrtf(fmaxf(msq - mean * mean, 0.f) + 1e-5f);
  unsigned u = mxb[i];
  unsigned bits = (u & 0x80000000u) ? (u & 0x7FFFFFFFu) : ~u;
  float mxv = __uint_as_float(bits);
  if ((bits & 0x7F800000u) == 0x7F800000u) mxv = 0.f;
  u16* cb = catb + (size_t)n * 512;
  cb[c]       = f2b(x[(size_t)n * 128 + c]);
  cb[128 + c] = f2b(mean);
  cb[256 + c] = f2b(mxv);
  cb[384 + c] = f2b(sd);
}

// ---------------------------------------------------------------------------
// GRU elementwise combine
// ---------------------------------------------------------------------------
__global__ void gru_kernel(const float* __restrict__ gi, const float* __restrict__ gh,
                           const float* __restrict__ h, float* __restrict__ hout, int total)
{
  int i = blockIdx.x * blockDim.x + threadIdx.x;
  if (i >= total) return;
  int n = i >> 7, c = i & 127;
  const float* gin = gi + (size_t)n * 384;
  const float* ghn = gh + (size_t)n * 384;
  float ir = gin[c], iz = gin[128 + c], inn = gin[256 + c];
  float hr = ghn[c], hz = ghn[128 + c], hn = ghn[256 + c];
  float r = 1.f / (1.f + __expf(-(ir + hr)));
  float z = 1.f / (1.f + __expf(-(iz + hz)));
  float nn = tanhf(inn + r * hn);
  hout[i] = (1.f - z) * nn + z * h[i];
}

// ---------------------------------------------------------------------------
// ecat = [med bf16 (M,64) | bf16(ea fp32) (M,64)] -> out bf16 (M,128)
// ---------------------------------------------------------------------------
__global__ void concat_b_kernel(const u16* __restrict__ med, const float* __restrict__ ea,
                                u16* __restrict__ out, long total)
{
  long i = (long)blockIdx.x * blockDim.x + threadIdx.x;
  if (i >= total) return;
  long e = i >> 7;
  int c = (int)(i & 127);
  out[i] = (c < 64) ? med[e * 64 + c] : f2b(ea[e * 64 + (c - 64)]);
}

// ---------------------------------------------------------------------------
extern "C" void kernel_launch(void* const* d_in, const int* in_sizes, int n_in,
                              void* d_out, int out_size, void* d_ws, size_t ws_size,
                              hipStream_t stream)
{
  const int N_ = GN, E_ = GE, Np = GNP;

  const float* x_in   = (const float*)d_in[0];
  const int*   src    = (const int*)d_in[1];
  const int*   dst    = src + E_;
  const float* ea_in  = (const float*)d_in[2];
  const float* enc_W  = (const float*)d_in[3];
  const float* enc_b  = (const float*)d_in[4];
  const float* pre_W1 = (const float*)d_in[5];
  const float* pre_b1 = (const float*)d_in[6];
  const float* pre_W2 = (const float*)d_in[7];
  const float* pre_b2 = (const float*)d_in[8];
  const float* post_W1 = (const float*)d_in[9];
  const float* post_b1 = (const float*)d_in[10];
  const float* post_W2 = (const float*)d_in[11];
  const float* post_b2 = (const float*)d_in[12];
  const float* lin_W  = (const float*)d_in[13];
  const float* lin_b  = (const float*)d_in[14];
  const float* gru_Wi = (const float*)d_in[15];
  const float* gru_Wh = (const float*)d_in[16];
  const float* gru_bi = (const float*)d_in[17];
  const float* gru_bh = (const float*)d_in[18];
  const float* fcu_W1 = (const float*)d_in[19];
  const float* fcu_b1 = (const float*)d_in[20];
  const float* fcu_W2 = (const float*)d_in[21];
  const float* fcu_b2 = (const float*)d_in[22];
  const float* fcv_W1 = (const float*)d_in[23];
  const float* fcv_b1 = (const float*)d_in[24];
  const float* fcv_W2 = (const float*)d_in[25];
  const float* fcv_b2 = (const float*)d_in[26];
  const float* fc_W1  = (const float*)d_in[27];
  const float* fc_b1  = (const float*)d_in[28];
  const float* fc_W2  = (const float*)d_in[29];
  const float* fc_b2  = (const float*)d_in[30];
  const float* eu_W1  = (const float*)d_in[31];
  const float* eu_b1  = (const float*)d_in[32];
  const float* eu_W2  = (const float*)d_in[33];
  const float* eu_b2  = (const float*)d_in[34];

  // ---- workspace arena ----
  size_t used = 0;
  char* w = (char*)d_ws;
  auto alloc = [&](size_t bytes) {
    char* p = w + used;
    used += (bytes + 255) & ~(size_t)255;
    return p;
  };
  float*    sumb   = (float*)alloc((size_t)N_ * 512 * 4);   // [t][n][128]
  float*    sumsqb = (float*)alloc((size_t)N_ * 512 * 4);
  unsigned* mxb    = (unsigned*)alloc((size_t)N_ * 512 * 4);
  float*    q1   = (float*)alloc((size_t)Np * 64 * 4);
  u16*      q2b  = (u16*)alloc((size_t)Np * 128 * 2);
  u16*      mbb  = (u16*)alloc((size_t)Np * 128 * 2);
  float*    gib  = (float*)alloc((size_t)Np * 384 * 4);
  float*    ghb  = (float*)alloc((size_t)Np * 384 * 4);
  float*    Hb   = (float*)alloc((size_t)N_ * 128 * 4);
  u16*      xb   = (u16*)alloc((size_t)Np * 128 * 2);
  u16*      catb = (u16*)alloc((size_t)Np * 512 * 2);
  u16*      eab  = (u16*)alloc((size_t)E_ * 64 * 2);
  // bf16 transposed weights
  u16* encWt  = (u16*)alloc((size_t)GL * 128 * 64 * 2);
  u16* preW1t = (u16*)alloc((size_t)GL * GT * 128 * 384 * 2);
  u16* preW2t = (u16*)alloc((size_t)GL * GT * 128 * 128 * 2);
  u16* postW1t = (u16*)alloc((size_t)GL * GT * 64 * 512 * 2);
  float* postb1p = (float*)alloc((size_t)GL * GT * 64 * 4);
  u16* linWt  = (u16*)alloc((size_t)GL * 128 * 128 * 2);
  u16* gruWit = (u16*)alloc((size_t)384 * 128 * 2);
  u16* gruWht = (u16*)alloc((size_t)384 * 128 * 2);
  u16* fcuW1t = (u16*)alloc((size_t)256 * 128 * 2);
  u16* fcuW2t = (u16*)alloc((size_t)256 * 256 * 2);
  u16* fcvW1t = (u16*)alloc((size_t)256 * 128 * 2);
  u16* fcvW2t = (u16*)alloc((size_t)256 * 256 * 2);
  u16* fcW1t  = (u16*)alloc((size_t)256 * 256 * 2);
  u16* fcW2t  = (u16*)alloc((size_t)64 * 256 * 2);
  u16* euW1t  = (u16*)alloc((size_t)128 * 128 * 2);
  u16* euW2t  = (u16*)alloc((size_t)64 * 128 * 2);
  int* eidx   = (int*)alloc((size_t)E_ * 4);
  int* degb   = (int*)alloc((size_t)(N_ + 1) * 4);
  int* rowptr = (int*)alloc((size_t)(N_ + 1) * 4);
  int* cursor = (int*)alloc((size_t)(N_ + 1) * 4);

  // chunk arena: 2048 B/row.
  //  conv:  [hball Ec*1024 | region2 Ec*1024 (Acat 768 -> msgb 4x256)]
  //  edge:  [C1b Ec*512 | C2b Ec*512 | C3b Ec*512]
  size_t avail = (ws_size > used + 4096) ? (ws_size - used - 4096) : 0;
  long Ec = (long)(avail / 2048);
  if (Ec > E_) Ec = E_;
  Ec &= ~255L;
  if (Ec < 256) return;   // ws too small: fail cleanly
  char* arena = alloc((size_t)Ec * 2048);
  if (used > ws_size) return;
  const int nchunks = (int)((E_ + Ec - 1) / Ec);
  u16*   hball = (u16*)arena;                          // Ec x 512 bf16
  u16*   Acatb = (u16*)(arena + (size_t)Ec * 1024);    // Ec x 384 bf16
  u16*   msgb  = (u16*)(arena + (size_t)Ec * 1024);    // 4 x Ec x 128 bf16
  u16* C1b = (u16*)arena;
  u16* C2b = (u16*)(arena + (size_t)Ec * 512);
  u16* C3b = (u16*)(arena + (size_t)Ec * 1024);

  float* out = (float*)d_out;
  float* EAp = out + (size_t)N_ * 128;   // ea state lives in d_out

  // ---- one-time setup ----
  hipMemsetAsync(degb, 0, (size_t)N_ * 4, stream);
  deg_kernel<<<(E_ + 255) / 256, 256, 0, stream>>>(dst, degb, E_);
  scan_kernel<<<1, 256, 0, stream>>>(degb, rowptr, N_);
  hipMemcpyAsync(cursor, rowptr, (size_t)N_ * 4, hipMemcpyDeviceToDevice, stream);
  scatter_kernel<<<(E_ + 255) / 256, 256, 0, stream>>>(dst, cursor, eidx, E_);

  hipMemsetAsync(postW1t, 0, (size_t)GL * GT * 64 * 512 * 2, stream);
  hipMemsetAsync(postb1p, 0, (size_t)GL * GT * 64 * 4, stream);
  {
    dim3 gb(48, GL);
    wtb_kernel<<<gb, 256, 0, stream>>>(enc_W, encWt, 64, 128, 128 * 64);
    wtb_kernel<<<gb, 256, 0, stream>>>(lin_W, linWt, 128, 128, 128 * 128);
    dim3 gt(48, GL * GT);
    wtb_kernel<<<gt, 256, 0, stream>>>(pre_W1, preW1t, 384, 128, 128 * 384);
    wtb_kernel<<<gt, 256, 0, stream>>>(pre_W2, preW2t, 128, 128, 128 * 128);
    wtb_kernel<<<gt, 256, 0, stream>>>(post_W1, postW1t, 512, 32, 64 * 512);
    dim3 g1(48, 1);
    wtb_kernel<<<g1, 256, 0, stream>>>(gru_Wi, gruWit, 128, 384, 384 * 128);
    wtb_kernel<<<g1, 256, 0, stream>>>(gru_Wh, gruWht, 128, 384, 384 * 128);
    wtb_kernel<<<g1, 256, 0, stream>>>(fcu_W1, fcuW1t, 128, 256, 256 * 128);
    wtb_kernel<<<g1, 256, 0, stream>>>(fcu_W2, fcuW2t, 256, 256, 256 * 256);
    wtb_kernel<<<g1, 256, 0, stream>>>(fcv_W1, fcvW1t, 128, 256, 256 * 128);
    wtb_kernel<<<g1, 256, 0, stream>>>(fcv_W2, fcvW2t, 256, 256, 256 * 256);
    wtb_kernel<<<g1, 256, 0, stream>>>(fc_W1, fcW1t, 256, 256, 256 * 256);
    wtb_kernel<<<g1, 256, 0, stream>>>(fc_W2, fcW2t, 256, 64, 64 * 256);
    wtb_kernel<<<g1, 256, 0, stream>>>(eu_W1, euW1t, 128, 128, 128 * 128);
    wtb_kernel<<<g1, 256, 0, stream>>>(eu_W2, euW2t, 128, 64, 64 * 128);
  }
  biaspad_kernel<<<(GL * GT * 32 + 255) / 256, 256, 0, stream>>>(
      post_b1, postb1p, GL * GT * 32);

  f2b_kernel<<<(N_ * 128 + 255) / 256, 256, 0, stream>>>(x_in, xb, N_ * 128);
  f2b_kernel<<<(E_ * 64 + 255) / 256, 256, 0, stream>>>(ea_in, eab, E_ * 64);

  const float* x_cur = x_in;
  const float* ea_cur = ea_in;

  for (int l = 0; l < GL; ++l) {
    // ---- PNA conv ----
    agg_init_kernel<<<(N_ * 512 + 255) / 256, 256, 0, stream>>>(sumb, sumsqb, mxb, N_ * 512);
    for (int c = 0; c < nchunks; ++c) {
      long p0 = (long)c * Ec;
      int Mc = (int)(((long)E_ - p0 < Ec) ? ((long)E_ - p0) : Ec);
      dim3 gEnc(1, Mc / 128), gH(4, Mc / 128), gMsg(1, Mc / 128);
      // enc chunk (gathered bf16) -> Acat cols 256..383
      mg2_k<false, true, false, true><<<gEnc, 256, 0, stream>>>(
          eab, nullptr, eidx + p0, encWt + (size_t)l * 128 * 64,
          enc_b + (size_t)l * 128, Acatb + 256, Mc, 128, 64, 64, 384);
      build_acat_kernel<<<(Mc * 32 + 255) / 256, 256, 0, stream>>>(
          xb, eidx, src, dst, p0, Mc, Acatb);
      // h (all towers): Mc x 512, K=384
      mg2_k<true, false, false, true><<<gH, 256, 0, stream>>>(
          Acatb, nullptr, nullptr, preW1t + (size_t)l * 512 * 384,
          pre_b1 + (size_t)l * 512, hball, Mc, 512, 384, 384, 512);
      // msg per tower -> msgb[t] (bf16)
      for (int t = 0; t < GT; ++t) {
        mg2_k<false, false, false, true><<<gMsg, 256, 0, stream>>>(
            hball + t * 128, nullptr, nullptr,
            preW2t + ((size_t)l * GT + t) * 128 * 128,
            pre_b2 + (size_t)l * 512 + t * 128,
            msgb + (size_t)t * Ec * 128, Mc, 128, 128, 512, 128);
      }
      // merge all towers
      dim3 gMg(Mc / 64, GT);
      agg_merge_kernel<<<gMg, 128, 0, stream>>>(
          msgb, (size_t)Ec * 128, eidx, dst, p0, sumb, sumsqb, mxb, N_);
    }
    for (int t = 0; t < GT; ++t) {
      finalize_kernel<<<(N_ * 128 + 255) / 256, 256, 0, stream>>>(
          sumb + (size_t)t * N_ * 128, sumsqb + (size_t)t * N_ * 128,
          mxb + (size_t)t * N_ * 128, rowptr, x_cur, catb, N_ * 128);
      dim3 gP1(1, Np / 64);
      mgemm_k<true, false, false, false><<<gP1, 256, 0, stream>>>(
          catb, nullptr, nullptr, postW1t + ((size_t)l * GT + t) * 64 * 512,
          postb1p + ((size_t)l * GT + t) * 64, q1, Np, 64, 512, 512, 64);
      dim3 gP2(1, (N_ + 63) / 64);
      gemm_k<false, false, true><<<gP2, 256, 0, stream>>>(
          q1, nullptr, post_W2 + ((size_t)l * GT + t) * 32 * 32,
          post_b2 + ((size_t)l * GT + t) * 32,
          q2b + t * 32, N_, 32, 32, 64, 32, 128);
    }
    {
      dim3 gL(1, Np / 128), gG(3, Np / 128);
      mg2_k<false, false, false, true><<<gL, 256, 0, stream>>>(
          q2b, nullptr, nullptr, linWt + (size_t)l * 128 * 128,
          lin_b + (size_t)l * 128, mbb, Np, 128, 128, 128, 128);
      mg2_k<false, false, false, false><<<gG, 256, 0, stream>>>(
          mbb, nullptr, nullptr, gruWit, gru_bi, gib, Np, 384, 128, 128, 384);
      mg2_k<false, false, false, false><<<gG, 256, 0, stream>>>(
          xb, nullptr, nullptr, gruWht, gru_bh, ghb, Np, 384, 128, 128, 384);
    }
    gru_kernel<<<(N_ * 128 + 255) / 256, 256, 0, stream>>>(gib, ghb, x_cur, Hb, N_ * 128);
    f2b_kernel<<<(N_ * 128 + 255) / 256, 256, 0, stream>>>(Hb, xb, N_ * 128);

    // ---- edge update (chunked, bf16 MFMA chain) ----
    for (int c = 0; c < nchunks; ++c) {
      long e0 = (long)c * Ec;
      int Mc = (int)(((long)E_ - e0 < Ec) ? ((long)E_ - e0) : Ec);
      dim3 g2m(2, Mc / 128), g1m(1, Mc / 128), g64(1, Mc / 64);
      mg2_k<true, true, false, true><<<g2m, 256, 0, stream>>>(
          xb, nullptr, src + e0, fcuW1t, fcu_b1, C1b, Mc, 256, 128, 128, 256);
      mg2_k<true, false, false, true><<<g2m, 256, 0, stream>>>(
          C1b, nullptr, nullptr, fcuW2t, fcu_b2, C2b, Mc, 256, 256, 256, 256);
      mg2_k<true, true, false, true><<<g2m, 256, 0, stream>>>(
          xb, nullptr, dst + e0, fcvW1t, fcv_b1, C1b, Mc, 256, 128, 128, 256);
      mg2_k<true, false, false, true><<<g2m, 256, 0, stream>>>(
          C1b, nullptr, nullptr, fcvW2t, fcv_b2, C3b, Mc, 256, 256, 256, 256);
      mg2_k<true, false, true, true><<<g2m, 256, 0, stream>>>(
          C2b, C3b, nullptr, fcW1t, fc_b1, C1b, Mc, 256, 256, 256, 256);
      mgemm_k<true, false, false, true><<<g64, 256, 0, stream>>>(
          C1b, nullptr, nullptr, fcW2t, fc_b2, C2b, Mc, 64, 256, 256, 64);
      concat_b_kernel<<<(int)(((long)Mc * 128 + 255) / 256), 256, 0, stream>>>(
          C2b, ea_cur + e0 * 64, C3b, (long)Mc * 128);
      mg2_k<true, false, false, true><<<g1m, 256, 0, stream>>>(
          C3b, nullptr, nullptr, euW1t, eu_b1, C1b, Mc, 128, 128, 128, 128);
      mgemm_k<false, false, false, false><<<g64, 256, 0, stream>>>(
          C1b, nullptr, nullptr, euW2t, eu_b2, EAp + e0 * 64, Mc, 64, 128, 128, 64);
    }
    f2b_kernel<<<(E_ * 64 + 255) / 256, 256, 0, stream>>>(EAp, eab, E_ * 64);

    x_cur = Hb;
    ea_cur = EAp;
  }

  // outputs: [out (N*128) | ea (in place) | out (N*128)]
  hipMemcpyAsync(out, x_cur, (size_t)N_ * 128 * 4, hipMemcpyDeviceToDevice, stream);
  hipMemcpyAsync(out + (size_t)N_ * 128 + (size_t)E_ * 64, x_cur,
                 (size_t)N_ * 128 * 4, hipMemcpyDeviceToDevice, stream);
}